// Round 10
// baseline (308.622 us; speedup 1.0000x reference)
//
#include <hip/hip_runtime.h>
#include <type_traits>

// ---------------------------------------------------------------------------
// GPT block forward: B=2, S=2048, D=1024, H=16, DH=64
// Round 10: GEMM -> single-buffer BK=64 (32/24 KiB LDS, 5-6 blocks/CU for
// wave-level latency hiding per m97/m114), full row&7 granule-XOR swizzle
// (2-lane/bank-group slices = conflict-free). Attention unchanged (round 9).
// ---------------------------------------------------------------------------

typedef unsigned short u16;
typedef short s16x8 __attribute__((ext_vector_type(8)));
typedef unsigned short u16x4 __attribute__((ext_vector_type(4)));
typedef float f32x4 __attribute__((ext_vector_type(4)));
typedef float f32x16 __attribute__((ext_vector_type(16)));

__device__ __forceinline__ u16 f2b(float f) {
    union { float f; unsigned u; } x{f};
    unsigned r = x.u + 0x7FFFu + ((x.u >> 16) & 1u);  // RNE
    return (u16)(r >> 16);
}

__device__ __forceinline__ float b2f(u16 v) {
    union { unsigned u; float f; } x;
    x.u = ((unsigned)v) << 16;
    return x.f;
}

__device__ __forceinline__ f32x4 mfma16(s16x8 a, s16x8 b, f32x4 c) {
    return __builtin_amdgcn_mfma_f32_16x16x32_bf16(a, b, c, 0, 0, 0);
}

__device__ __forceinline__ f32x16 mfma32(s16x8 a, s16x8 b, f32x16 c) {
    return __builtin_amdgcn_mfma_f32_32x32x16_bf16(a, b, c, 0, 0, 0);
}

__device__ __forceinline__ int cvtpk(float a, float b) {
    int r;
    asm("v_cvt_pk_bf16_f32 %0, %1, %2" : "=v"(r) : "v"(a), "v"(b));
    return r;
}

__device__ __forceinline__ void gld_lds16(const u16* g, u16* l) {
    __builtin_amdgcn_global_load_lds(
        (const __attribute__((address_space(1))) void*)g,
        (__attribute__((address_space(3))) void*)l, 16, 0, 0);
}

// --------------------------- fp32 -> bf16 convert ---------------------------
__global__ __launch_bounds__(256) void cvt_bf16(const float* __restrict__ in,
                                                u16* __restrict__ out, int n4) {
    int i = blockIdx.x * 256 + threadIdx.x;
    if (i < n4) {
        float4 v = ((const float4*)in)[i];
        u16x4 o = {f2b(v.x), f2b(v.y), f2b(v.z), f2b(v.w)};
        ((u16x4*)out)[i] = o;
    }
}

// ------------------- transpose fp32 [K,N] -> bf16 [N,K] ---------------------
__global__ __launch_bounds__(256) void transpose_bf16(const float* __restrict__ W,
                                                      u16* __restrict__ WT,
                                                      int K, int N) {
    __shared__ float t[32][33];
    int tx = threadIdx.x & 31, ty = threadIdx.x >> 5;
    int n0 = blockIdx.x * 32, k0 = blockIdx.y * 32;
    #pragma unroll
    for (int r = ty; r < 32; r += 8)
        t[r][tx] = W[(size_t)(k0 + r) * N + n0 + tx];
    __syncthreads();
    #pragma unroll
    for (int r = ty; r < 32; r += 8)
        WT[(size_t)(n0 + r) * K + k0 + tx] = f2b(t[tx][r]);
}

// ------------------ MFMA GEMM, single-buffer BK=64 --------------------------
// C[M,ldc] = A[M,K]@BT[N,K]^T + bias. BM=128, BK=64, 4 waves (2x2), wave tile
// 64 x BN/2. LDS 32 KiB (BN=128) -> 5 blocks/CU: wave-TLP hides the barrier
// drain (m97/m114). Granule swizzle: LDS(row,g) = Global(row, g^(row&7));
// read slices hit 2 lanes/bank-group (free, m136).
template<int BN, bool GELU, typename OT>
__global__ __launch_bounds__(256) void gemm_sb(const u16* __restrict__ A,
                                               const u16* __restrict__ BT,
                                               const float* __restrict__ bias,
                                               OT* __restrict__ C,
                                               int M, int N, int K, int ldc) {
    constexpr int NF = BN / 32;          // n-frags per wave
    constexpr int BNI = BN / 32;         // B staging instrs
    __shared__ u16 As[128 * 64];
    __shared__ u16 Bs[BN * 64];

    int t = threadIdx.x;
    int w = t >> 6, l = t & 63, l16 = l & 15, lh = l >> 4;
    int wr = w >> 1, wc = w & 1;

    // bijective XCD swizzle (grids all % 8 == 0), M-fastest within chunk
    int nbm = M >> 7;
    int cpx = gridDim.x >> 3;
    int id = blockIdx.x;
    int id2 = (id & 7) * cpx + (id >> 3);
    size_t m0 = (size_t)(id2 % nbm) * 128;
    size_t n0 = (size_t)(id2 / nbm) * BN;

    // staging: instr j covers granules j*256+t; row = j*32 + (t>>3), gc = t&7;
    // source granule pre-XORed with row&7; LDS dest linear.
    int rowA = t >> 3;
    int gc2 = (t & 7) ^ (rowA & 7);
    const u16* Ag = A + (m0 + rowA) * (size_t)K + gc2 * 8;
    const u16* Bg = BT + (n0 + rowA) * (size_t)K + gc2 * 8;
    int wbase = w * 512;                 // per-wave linear LDS base (u16)

    f32x4 acc[4][NF] = {};
    int rx = (l16 & 7) * 8;              // read-side granule XOR (bytes: *16)

    for (int k0 = 0; k0 < K; k0 += 64) {
        #pragma unroll
        for (int j = 0; j < 4; ++j)
            gld_lds16(Ag + k0 + (size_t)j * 32 * K, &As[j * 2048 + wbase]);
        #pragma unroll
        for (int j = 0; j < BNI; ++j)
            gld_lds16(Bg + k0 + (size_t)j * 32 * K, &Bs[j * 2048 + wbase]);
        __syncthreads();                 // vmcnt(0) drain + barrier

        #pragma unroll
        for (int ks = 0; ks < 2; ++ks) {
            s16x8 af[4], bf[NF];
            #pragma unroll
            for (int fm = 0; fm < 4; ++fm) {
                int row = wr * 64 + fm * 16 + l16;
                int col = ((ks * 4 + lh) * 8) ^ rx;
                af[fm] = *(const s16x8*)&As[row * 64 + col];
            }
            #pragma unroll
            for (int fn = 0; fn < NF; ++fn) {
                int row = wc * (BN / 2) + fn * 16 + l16;
                int col = ((ks * 4 + lh) * 8) ^ rx;
                bf[fn] = *(const s16x8*)&Bs[row * 64 + col];
            }
            #pragma unroll
            for (int fm = 0; fm < 4; ++fm)
                #pragma unroll
                for (int fn = 0; fn < NF; ++fn)
                    acc[fm][fn] = mfma16(af[fm], bf[fn], acc[fm][fn]);
        }
        __syncthreads();                 // protect LDS overwrite
    }

    #pragma unroll
    for (int fn = 0; fn < NF; ++fn) {
        size_t col = n0 + wc * (BN / 2) + fn * 16 + l16;
        float bs = bias[col];
        #pragma unroll
        for (int fm = 0; fm < 4; ++fm) {
            size_t row0 = m0 + wr * 64 + fm * 16 + lh * 4;
            #pragma unroll
            for (int i = 0; i < 4; ++i) {
                float v = acc[fm][fn][i] + bs;
                if constexpr (GELU) {
                    float x3 = v * v * v;
                    v = 0.5f * v * (1.f + tanhf(0.7978845608f * (v + 0.044715f * x3)));
                }
                if constexpr (std::is_same<OT, u16>::value)
                    C[(row0 + i) * ldc + col] = f2b(v);
                else
                    C[(row0 + i) * ldc + col] = v;
            }
        }
    }
}

// --------------------------- causal attention -------------------------------
// kv-split x3 (round 9, verified): block = (third, pair pr, bh); writes
// unnormalized O partials + (m,lr) stats; merge_attn combines exactly.
__global__ __launch_bounds__(256) void attn_kernel(const u16* __restrict__ qkv,
                                                   u16* __restrict__ p0,
                                                   u16* __restrict__ p1,
                                                   u16* __restrict__ p2,
                                                   float2* __restrict__ stats) {
    constexpr int S = 2048, D3 = 3072, Dm = 1024;
    __shared__ u16 Kl[2][64 * 64];
    __shared__ u16 Vt[2][64 * 64];

    int t = threadIdx.x;
    int w = t >> 6, l = t & 63;
    int l32 = l & 31, hi = l >> 5;
    int bid = blockIdx.x;
    int bh = bid & 31;
    int pr = (bid >> 5) & 7;
    int third = bid >> 8;               // 0..2
    int b = bh >> 4, h = bh & 15;
    size_t base = (size_t)b * S * D3;

    u16* pout = third == 0 ? p0 : (third == 1 ? p1 : p2);

    int rK0 = t >> 3, gK = t & 7;
    int rK1 = rK0 + 32;
    size_t koff0 = (size_t)rK0 * D3 + (size_t)((gK ^ (rK0 & 7)) * 8);
    size_t koff1 = (size_t)rK1 * D3 + (size_t)((gK ^ (rK1 & 7)) * 8);
    const u16* kbase = qkv + base + Dm + h * 64;
    const u16* vbase = qkv + base + 2 * Dm + h * 64 + w * 16;

    constexpr float cexp = 0.18033688011112042f;   // 0.125 * log2(e)
    constexpr float THR = 64.0f;                    // defer-max threshold
    int xg = l32 & 7;

    #pragma unroll 1
    for (int ph = 0; ph < 2; ++ph) {
        int qt = ph ? (15 - pr) : pr;
        int qb = qt * 128 + w * 32;
        int nst = 2 * (qt + 1);
        int c0 = (nst * third) / 3;
        int c1 = (nst * (third + 1)) / 3;

        f32x16 O0 = {}, O1 = {};
        float m = -1e30f, lr = 0.f;

        if (c0 < c1) {
            s16x8 qf[4];
            const u16* qp = qkv + base + (size_t)(qb + l32) * D3 + h * 64 + hi * 8;
            #pragma unroll
            for (int kk = 0; kk < 4; ++kk)
                qf[kk] = *(const s16x8*)(qp + kk * 16);

            size_t kc0 = (size_t)c0 * 64 * D3;
            gld_lds16(kbase + kc0 + koff0, &Kl[0][w * 512]);
            gld_lds16(kbase + kc0 + koff1, &Kl[0][2048 + w * 512]);
            {
                const u16* vp = vbase + (size_t)(c0 * 64 + l) * D3;
                s16x8 pv0 = *(const s16x8*)vp;
                s16x8 pv1 = *(const s16x8*)(vp + 8);
                #pragma unroll
                for (int e = 0; e < 8; ++e) {
                    int d0 = w * 16 + e, d1 = w * 16 + 8 + e;
                    Vt[0][d0 * 64 + (l ^ ((d0 & 7) << 3))] = (u16)pv0[e];
                    Vt[0][d1 * 64 + (l ^ ((d1 & 7) << 3))] = (u16)pv1[e];
                }
            }
            __syncthreads();

            #pragma unroll 1
            for (int sc = c0; sc < c1; ++sc) {
                int cur = (sc - c0) & 1;
                bool pre = (sc + 1 < c1);
                s16x8 v0, v1;
                if (pre) {
                    size_t koffc = (size_t)(sc + 1) * 64 * D3;
                    gld_lds16(kbase + koffc + koff0, &Kl[cur ^ 1][w * 512]);
                    gld_lds16(kbase + koffc + koff1, &Kl[cur ^ 1][2048 + w * 512]);
                    const u16* vp = vbase + (size_t)((sc + 1) * 64 + l) * D3;
                    v0 = *(const s16x8*)vp;
                    v1 = *(const s16x8*)(vp + 8);
                }

                int kvb = sc * 64;
                int navail = ((qb - kvb) >> 5) + 1;
                if (navail > 0) {
                    if (navail > 2) navail = 2;
                    const u16* Kc = Kl[cur];
                    const u16* Vc = Vt[cur];
                    f32x16 sa0 = {}, sa1 = {};
                    #pragma unroll
                    for (int kk = 0; kk < 4; ++kk) {
                        s16x8 kf = *(const s16x8*)&Kc[l32 * 64 + (((2 * kk + hi) ^ xg) * 8)];
                        sa0 = mfma32(kf, qf[kk], sa0);
                    }
                    if (navail == 2) {
                        #pragma unroll
                        for (int kk = 0; kk < 4; ++kk) {
                            s16x8 kf = *(const s16x8*)&Kc[(32 + l32) * 64 + (((2 * kk + hi) ^ xg) * 8)];
                            sa1 = mfma32(kf, qf[kk], sa1);
                        }
                    }
                    bool diag0 = (kvb == qb);
                    bool diag1 = (kvb + 32 == qb);
                    float p[32];
                    float mx = -1e30f;
                    #pragma unroll
                    for (int reg = 0; reg < 16; ++reg) {
                        int kvloc = (reg & 3) + 8 * (reg >> 2) + 4 * hi;
                        float s0 = sa0[reg];
                        if (diag0 && kvloc > l32) s0 = -1e30f;
                        p[reg] = s0;
                        mx = fmaxf(mx, s0);
                    }
                    if (navail == 2) {
                        #pragma unroll
                        for (int reg = 0; reg < 16; ++reg) {
                            int kvloc = (reg & 3) + 8 * (reg >> 2) + 4 * hi;
                            float s1 = sa1[reg];
                            if (diag1 && kvloc > l32) s1 = -1e30f;
                            p[16 + reg] = s1;
                            mx = fmaxf(mx, s1);
                        }
                    }
                    mx = fmaxf(mx, __shfl_xor(mx, 32));
                    if (!__all(mx <= m + THR)) {          // defer-max (T13)
                        float mn = fmaxf(m, mx);
                        float a_ = exp2f(cexp * (m - mn));
                        m = mn;
                        #pragma unroll
                        for (int reg = 0; reg < 16; ++reg) {
                            int src = (reg & 3) + 8 * (reg >> 2) + 4 * hi;
                            float aq = __shfl(a_, src);
                            O0[reg] *= aq;
                            O1[reg] *= aq;
                        }
                        lr *= a_;
                    }
                    float rs = 0.f;
                    #pragma unroll
                    for (int reg = 0; reg < 16; ++reg) {
                        p[reg] = exp2f(cexp * (p[reg] - m));
                        rs += p[reg];
                    }
                    if (navail == 2) {
                        #pragma unroll
                        for (int reg = 16; reg < 32; ++reg) {
                            p[reg] = exp2f(cexp * (p[reg] - m));
                            rs += p[reg];
                        }
                    }
                    rs += __shfl_xor(rs, 32);
                    lr += rs;

                    #pragma unroll
                    for (int c = 0; c < 4; ++c) {
                        if (c < navail * 2) {
                            int pb = (c >> 1) * 16 + (c & 1) * 8;
                            int pk01 = cvtpk(p[pb + 0], p[pb + 1]);
                            int pk23 = cvtpk(p[pb + 2], p[pb + 3]);
                            int pk45 = cvtpk(p[pb + 4], p[pb + 5]);
                            int pk67 = cvtpk(p[pb + 6], p[pb + 7]);
                            int sx01 = __shfl_xor(pk01, 32);
                            int sx23 = __shfl_xor(pk23, 32);
                            int sx45 = __shfl_xor(pk45, 32);
                            int sx67 = __shfl_xor(pk67, 32);
                            union { int i[4]; s16x8 v; } u;
                            u.i[0] = hi ? sx45 : pk01;
                            u.i[1] = hi ? sx67 : pk23;
                            u.i[2] = hi ? pk45 : sx01;
                            u.i[3] = hi ? pk67 : sx23;
                            int go = ((c * 2 + hi) ^ xg) * 8;
                            s16x8 vb0 = *(const s16x8*)&Vc[l32 * 64 + go];
                            O0 = mfma32(u.v, vb0, O0);
                            s16x8 vb1 = *(const s16x8*)&Vc[(32 + l32) * 64 + go];
                            O1 = mfma32(u.v, vb1, O1);
                        }
                    }
                }

                if (pre) {
                    #pragma unroll
                    for (int e = 0; e < 8; ++e) {
                        int d0 = w * 16 + e, d1 = w * 16 + 8 + e;
                        Vt[cur ^ 1][d0 * 64 + (l ^ ((d0 & 7) << 3))] = (u16)v0[e];
                        Vt[cur ^ 1][d1 * 64 + (l ^ ((d1 & 7) << 3))] = (u16)v1[e];
                    }
                }
                __syncthreads();
            }
        }

        size_t obase = (size_t)b * S * 1024 + h * 64;
        #pragma unroll
        for (int reg = 0; reg < 16; ++reg) {
            int src = (reg & 3) + 8 * (reg >> 2) + 4 * hi;
            size_t row = obase + (size_t)(qb + src) * 1024;
            pout[row + l32] = f2b(O0[reg]);
            pout[row + 32 + l32] = f2b(O1[reg]);
        }
        if (hi == 0) {
            float2 st; st.x = m; st.y = lr;
            stats[third * 65536 + ((b * 2048 + qb + l32) * 16 + h)] = st;
        }
    }
}

// ------------------------- attention partial merge --------------------------
__global__ __launch_bounds__(256) void merge_attn(u16* __restrict__ p0,
                                                  const u16* __restrict__ p1,
                                                  const u16* __restrict__ p2,
                                                  const float2* __restrict__ stats) {
    constexpr float cexp = 0.18033688011112042f;
    int gid = blockIdx.x * 256 + threadIdx.x;    // [0, 65536*4)
    int rh = gid >> 2;
    int dc = (gid & 3) * 16;
    int R = rh >> 4, h = rh & 15;
    size_t addr = (size_t)R * 1024 + h * 64 + dc;

    float2 s0 = stats[rh];
    float2 s1 = stats[65536 + rh];
    float2 s2 = stats[131072 + rh];
    float M = fmaxf(s0.x, fmaxf(s1.x, s2.x));
    float a0 = exp2f(cexp * (s0.x - M));
    float a1 = exp2f(cexp * (s1.x - M));
    float a2 = exp2f(cexp * (s2.x - M));
    float inv = 1.f / (a0 * s0.y + a1 * s1.y + a2 * s2.y);
    a0 *= inv; a1 *= inv; a2 *= inv;

    u16x4 o[4];
    #pragma unroll
    for (int j = 0; j < 4; ++j) {
        u16x4 q0 = *(const u16x4*)(p0 + addr + j * 4);
        u16x4 q1 = *(const u16x4*)(p1 + addr + j * 4);
        u16x4 q2 = *(const u16x4*)(p2 + addr + j * 4);
        #pragma unroll
        for (int e = 0; e < 4; ++e)
            o[j][e] = f2b(a0 * b2f(q0[e]) + a1 * b2f(q1[e]) + a2 * b2f(q2[e]));
    }
    #pragma unroll
    for (int j = 0; j < 4; ++j)
        *(u16x4*)(p0 + addr + j * 4) = o[j];
}

// --------------------- residual + LayerNorm (row = 1024) --------------------
template<bool WB>
__global__ __launch_bounds__(256) void resln(const float* __restrict__ xa,
                                             const float* __restrict__ xb2,
                                             const float* __restrict__ g,
                                             const float* __restrict__ be,
                                             float* __restrict__ outf,
                                             u16* __restrict__ outb) {
    int row = blockIdx.x;
    int t = threadIdx.x;
    size_t base = (size_t)row * 1024 + t * 4;
    float4 va = *(const float4*)(xa + base);
    float4 vb = *(const float4*)(xb2 + base);
    float v0 = va.x + vb.x, v1 = va.y + vb.y, v2 = va.z + vb.z, v3 = va.w + vb.w;
    float s1 = v0 + v1 + v2 + v3;
    float s2 = v0 * v0 + v1 * v1 + v2 * v2 + v3 * v3;
    #pragma unroll
    for (int off = 32; off >= 1; off >>= 1) {
        s1 += __shfl_down(s1, off);
        s2 += __shfl_down(s2, off);
    }
    __shared__ float r1[4], r2[4];
    if ((t & 63) == 0) { r1[t >> 6] = s1; r2[t >> 6] = s2; }
    __syncthreads();
    s1 = r1[0] + r1[1] + r1[2] + r1[3];
    s2 = r2[0] + r2[1] + r2[2] + r2[3];
    float mean = s1 * (1.f / 1024.f);
    float var = fmaxf((s2 - 1024.f * mean * mean) * (1.f / 1023.f), 0.f);
    float inv = 1.f / (sqrtf(var) + 1e-6f);
    int col = t * 4;
    float y0 = g[col + 0] * ((v0 - mean) * inv) + be[col + 0];
    float y1 = g[col + 1] * ((v1 - mean) * inv) + be[col + 1];
    float y2 = g[col + 2] * ((v2 - mean) * inv) + be[col + 2];
    float y3 = g[col + 3] * ((v3 - mean) * inv) + be[col + 3];
    float4 o = {y0, y1, y2, y3};
    *(float4*)(outf + base) = o;
    if constexpr (WB) {
        u16x4 ob = {f2b(y0), f2b(y1), f2b(y2), f2b(y3)};
        *(u16x4*)(outb + base) = ob;
    }
}

// ---------------------------------------------------------------------------
extern "C" void kernel_launch(void* const* d_in, const int* in_sizes, int n_in,
                              void* d_out, int out_size, void* d_ws, size_t ws_size,
                              hipStream_t stream) {
    (void)in_sizes; (void)n_in; (void)out_size; (void)ws_size;
    const float* x       = (const float*)d_in[0];
    const float* w_attn  = (const float*)d_in[1];
    const float* b_attn  = (const float*)d_in[2];
    const float* w_aproj = (const float*)d_in[3];
    const float* b_aproj = (const float*)d_in[4];
    const float* g1      = (const float*)d_in[5];
    const float* b1      = (const float*)d_in[6];
    const float* w_fc    = (const float*)d_in[7];
    const float* b_fc    = (const float*)d_in[8];
    const float* w_mproj = (const float*)d_in[9];
    const float* b_mproj = (const float*)d_in[10];
    const float* g2      = (const float*)d_in[11];
    const float* b2      = (const float*)d_in[12];
    float* out = (float*)d_out;

    constexpr int M = 4096;           // B*S
    constexpr int D = 1024;

    char* ws = (char*)d_ws;
    u16*   slotA = (u16*)ws;                         // 32 MiB: qkv -> h
    char*  pB    = ws + (32u << 20);                 //  8 MiB: xb -> attn part0/abuf -> nb
    char*  pC    = ws + (40u << 20);                 //  8 MiB: attn part1 -> wT
    char*  pD    = ws + (48u << 20);                 // 16 MiB: attn part2 -> aout -> mout
    char*  pE    = ws + (64u << 20);                 // 16 MiB: attn stats -> nbuf (fp32)

    u16*   xb    = (u16*)pB;
    u16*   wT    = (u16*)pC;
    u16*   qkv   = slotA;
    u16*   part0 = (u16*)pB;                         // becomes merged abuf
    u16*   part1 = (u16*)pC;
    u16*   part2 = (u16*)pD;
    float2* stat = (float2*)pE;
    u16*   abuf  = (u16*)pB;
    float* aout  = (float*)pD;
    float* nbuf  = (float*)pE;
    u16*   nb    = (u16*)pB;
    u16*   h     = slotA;
    float* mout  = (float*)pD;

    dim3 blk(256);

    cvt_bf16<<<dim3(4096), blk, 0, stream>>>(x, xb, M * D / 4);

    transpose_bf16<<<dim3(3072 / 32, 1024 / 32), blk, 0, stream>>>(w_attn, wT, 1024, 3072);
    gemm_sb<128, false, u16><<<dim3((M / 128) * (3072 / 128)), blk, 0, stream>>>(
        xb, wT, b_attn, qkv, M, 3072, 1024, 3072);

    attn_kernel<<<dim3(768), blk, 0, stream>>>(qkv, part0, part1, part2, stat);
    merge_attn<<<dim3(1024), blk, 0, stream>>>(part0, part1, part2, stat);

    transpose_bf16<<<dim3(1024 / 32, 1024 / 32), blk, 0, stream>>>(w_aproj, wT, 1024, 1024);
    gemm_sb<64, false, float><<<dim3((M / 128) * (1024 / 64)), blk, 0, stream>>>(
        abuf, wT, b_aproj, aout, M, 1024, 1024, 1024);

    resln<true><<<dim3(M), blk, 0, stream>>>(x, aout, g1, b1, nbuf, nb);

    transpose_bf16<<<dim3(4096 / 32, 1024 / 32), blk, 0, stream>>>(w_fc, wT, 1024, 4096);
    gemm_sb<128, true, u16><<<dim3((M / 128) * (4096 / 128)), blk, 0, stream>>>(
        nb, wT, b_fc, h, M, 4096, 1024, 4096);

    transpose_bf16<<<dim3(1024 / 32, 4096 / 32), blk, 0, stream>>>(w_mproj, wT, 4096, 1024);
    gemm_sb<64, false, float><<<dim3((M / 128) * (1024 / 64)), blk, 0, stream>>>(
        h, wT, b_mproj, mout, M, 1024, 4096, 1024);

    resln<false><<<dim3(M), blk, 0, stream>>>(nbuf, mout, g2, b2, out, nullptr);
}

// Round 11
// 300.627 us; speedup vs baseline: 1.0266x; 1.0266x over previous
//
#include <hip/hip_runtime.h>
#include <type_traits>

// ---------------------------------------------------------------------------
// GPT block forward: B=2, S=2048, D=1024, H=16, DH=64
// Round 11: gemm_db (round-9 double-buffer, measured best) + round-10's
// validated full row&7 granule-XOR swizzle (stage & read, 0 conflicts).
// Attention/merge/LN unchanged from round 9.
// ---------------------------------------------------------------------------

typedef unsigned short u16;
typedef short s16x8 __attribute__((ext_vector_type(8)));
typedef unsigned short u16x4 __attribute__((ext_vector_type(4)));
typedef float f32x4 __attribute__((ext_vector_type(4)));
typedef float f32x16 __attribute__((ext_vector_type(16)));

__device__ __forceinline__ u16 f2b(float f) {
    union { float f; unsigned u; } x{f};
    unsigned r = x.u + 0x7FFFu + ((x.u >> 16) & 1u);  // RNE
    return (u16)(r >> 16);
}

__device__ __forceinline__ float b2f(u16 v) {
    union { unsigned u; float f; } x;
    x.u = ((unsigned)v) << 16;
    return x.f;
}

__device__ __forceinline__ f32x4 mfma16(s16x8 a, s16x8 b, f32x4 c) {
    return __builtin_amdgcn_mfma_f32_16x16x32_bf16(a, b, c, 0, 0, 0);
}

__device__ __forceinline__ f32x16 mfma32(s16x8 a, s16x8 b, f32x16 c) {
    return __builtin_amdgcn_mfma_f32_32x32x16_bf16(a, b, c, 0, 0, 0);
}

__device__ __forceinline__ int cvtpk(float a, float b) {
    int r;
    asm("v_cvt_pk_bf16_f32 %0, %1, %2" : "=v"(r) : "v"(a), "v"(b));
    return r;
}

__device__ __forceinline__ void gld_lds16(const u16* g, u16* l) {
    __builtin_amdgcn_global_load_lds(
        (const __attribute__((address_space(1))) void*)g,
        (__attribute__((address_space(3))) void*)l, 16, 0, 0);
}

// --------------------------- fp32 -> bf16 convert ---------------------------
__global__ __launch_bounds__(256) void cvt_bf16(const float* __restrict__ in,
                                                u16* __restrict__ out, int n4) {
    int i = blockIdx.x * 256 + threadIdx.x;
    if (i < n4) {
        float4 v = ((const float4*)in)[i];
        u16x4 o = {f2b(v.x), f2b(v.y), f2b(v.z), f2b(v.w)};
        ((u16x4*)out)[i] = o;
    }
}

// ------------------- transpose fp32 [K,N] -> bf16 [N,K] ---------------------
__global__ __launch_bounds__(256) void transpose_bf16(const float* __restrict__ W,
                                                      u16* __restrict__ WT,
                                                      int K, int N) {
    __shared__ float t[32][33];
    int tx = threadIdx.x & 31, ty = threadIdx.x >> 5;
    int n0 = blockIdx.x * 32, k0 = blockIdx.y * 32;
    #pragma unroll
    for (int r = ty; r < 32; r += 8)
        t[r][tx] = W[(size_t)(k0 + r) * N + n0 + tx];
    __syncthreads();
    #pragma unroll
    for (int r = ty; r < 32; r += 8)
        WT[(size_t)(n0 + r) * K + k0 + tx] = f2b(t[tx][r]);
}

// ------------------ MFMA GEMM, 2-phase double-buffered ----------------------
// BM=128, BK=64, 4 waves (2x2), wave tile 64 x BN/2. Loads for tile k+1 issued
// before compute on tile k; single __syncthreads (vmcnt0+lgkm0 drain) per
// K-tile. Swizzle: LDS(row,g) = Global(row, g^(row&7)); reads XOR (l16&7) ->
// 2 lanes/bank-group (conflict-free, validated round 10).
template<int BN, bool GELU, typename OT>
__global__ __launch_bounds__(256) void gemm_db(const u16* __restrict__ A,
                                               const u16* __restrict__ BT,
                                               const float* __restrict__ bias,
                                               OT* __restrict__ C,
                                               int M, int N, int K, int ldc) {
    constexpr int NF = BN / 32;
    constexpr int BNI = BN / 32;
    __shared__ u16 As[2][128 * 64];
    __shared__ u16 Bs[2][BN * 64];

    int t = threadIdx.x;
    int w = t >> 6, l = t & 63, l16 = l & 15, lh = l >> 4;
    int wr = w >> 1, wc = w & 1;

    int nbm = M >> 7;
    int cpx = gridDim.x >> 3;
    int id = blockIdx.x;
    int id2 = (id & 7) * cpx + (id >> 3);
    size_t m0 = (size_t)(id2 % nbm) * 128;
    size_t n0 = (size_t)(id2 / nbm) * BN;

    // staging: granule g = j*256 + t; row = g>>3, phys col-granule = g&7,
    // source col-granule pre-XORed with row&7 (rule #21: same involution
    // as the read side). LDS dest linear.
    int rowA = t >> 3;
    int gc2 = (t & 7) ^ (rowA & 7);
    const u16* Ag = A + (m0 + rowA) * (size_t)K + gc2 * 8;
    const u16* Bg = BT + (n0 + rowA) * (size_t)K + gc2 * 8;
    int wbase = w * 512;

    f32x4 acc[4][NF] = {};
    int rx = (l16 & 7) * 8;              // read-side granule XOR (u16 units)

    #pragma unroll
    for (int j = 0; j < 4; ++j)
        gld_lds16(Ag + (size_t)j * 32 * K, &As[0][j * 2048 + wbase]);
    #pragma unroll
    for (int j = 0; j < BNI; ++j)
        gld_lds16(Bg + (size_t)j * 32 * K, &Bs[0][j * 2048 + wbase]);
    __syncthreads();

    int cur = 0;
    for (int k0 = 0; k0 < K; k0 += 64) {
        if (k0 + 64 < K) {               // stage next tile into buf cur^1
            const u16* Ap = Ag + k0 + 64;
            #pragma unroll
            for (int j = 0; j < 4; ++j)
                gld_lds16(Ap + (size_t)j * 32 * K, &As[cur ^ 1][j * 2048 + wbase]);
            const u16* Bp = Bg + k0 + 64;
            #pragma unroll
            for (int j = 0; j < BNI; ++j)
                gld_lds16(Bp + (size_t)j * 32 * K, &Bs[cur ^ 1][j * 2048 + wbase]);
        }
        __builtin_amdgcn_s_setprio(1);
        #pragma unroll
        for (int ks = 0; ks < 2; ++ks) {
            s16x8 af[4], bf[NF];
            #pragma unroll
            for (int fm = 0; fm < 4; ++fm) {
                int row = wr * 64 + fm * 16 + l16;
                int col = ((ks * 4 + lh) * 8) ^ rx;
                af[fm] = *(const s16x8*)&As[cur][row * 64 + col];
            }
            #pragma unroll
            for (int fn = 0; fn < NF; ++fn) {
                int row = wc * (BN / 2) + fn * 16 + l16;
                int col = ((ks * 4 + lh) * 8) ^ rx;
                bf[fn] = *(const s16x8*)&Bs[cur][row * 64 + col];
            }
            #pragma unroll
            for (int fm = 0; fm < 4; ++fm)
                #pragma unroll
                for (int fn = 0; fn < NF; ++fn)
                    acc[fm][fn] = mfma16(af[fm], bf[fn], acc[fm][fn]);
        }
        __builtin_amdgcn_s_setprio(0);
        __syncthreads();                 // vmcnt(0)+lgkmcnt(0) drain + barrier
        cur ^= 1;
    }

    #pragma unroll
    for (int fn = 0; fn < NF; ++fn) {
        size_t col = n0 + wc * (BN / 2) + fn * 16 + l16;
        float bs = bias[col];
        #pragma unroll
        for (int fm = 0; fm < 4; ++fm) {
            size_t row0 = m0 + wr * 64 + fm * 16 + lh * 4;
            #pragma unroll
            for (int i = 0; i < 4; ++i) {
                float v = acc[fm][fn][i] + bs;
                if constexpr (GELU) {
                    float x3 = v * v * v;
                    v = 0.5f * v * (1.f + tanhf(0.7978845608f * (v + 0.044715f * x3)));
                }
                if constexpr (std::is_same<OT, u16>::value)
                    C[(row0 + i) * ldc + col] = f2b(v);
                else
                    C[(row0 + i) * ldc + col] = v;
            }
        }
    }
}

// --------------------------- causal attention -------------------------------
// kv-split x3 (round 9, verified): block = (third, pair pr, bh); writes
// unnormalized O partials + (m,lr) stats; merge_attn combines exactly.
__global__ __launch_bounds__(256) void attn_kernel(const u16* __restrict__ qkv,
                                                   u16* __restrict__ p0,
                                                   u16* __restrict__ p1,
                                                   u16* __restrict__ p2,
                                                   float2* __restrict__ stats) {
    constexpr int S = 2048, D3 = 3072, Dm = 1024;
    __shared__ u16 Kl[2][64 * 64];
    __shared__ u16 Vt[2][64 * 64];

    int t = threadIdx.x;
    int w = t >> 6, l = t & 63;
    int l32 = l & 31, hi = l >> 5;
    int bid = blockIdx.x;
    int bh = bid & 31;
    int pr = (bid >> 5) & 7;
    int third = bid >> 8;               // 0..2
    int b = bh >> 4, h = bh & 15;
    size_t base = (size_t)b * S * D3;

    u16* pout = third == 0 ? p0 : (third == 1 ? p1 : p2);

    int rK0 = t >> 3, gK = t & 7;
    int rK1 = rK0 + 32;
    size_t koff0 = (size_t)rK0 * D3 + (size_t)((gK ^ (rK0 & 7)) * 8);
    size_t koff1 = (size_t)rK1 * D3 + (size_t)((gK ^ (rK1 & 7)) * 8);
    const u16* kbase = qkv + base + Dm + h * 64;
    const u16* vbase = qkv + base + 2 * Dm + h * 64 + w * 16;

    constexpr float cexp = 0.18033688011112042f;   // 0.125 * log2(e)
    constexpr float THR = 64.0f;                    // defer-max threshold
    int xg = l32 & 7;

    #pragma unroll 1
    for (int ph = 0; ph < 2; ++ph) {
        int qt = ph ? (15 - pr) : pr;
        int qb = qt * 128 + w * 32;
        int nst = 2 * (qt + 1);
        int c0 = (nst * third) / 3;
        int c1 = (nst * (third + 1)) / 3;

        f32x16 O0 = {}, O1 = {};
        float m = -1e30f, lr = 0.f;

        if (c0 < c1) {
            s16x8 qf[4];
            const u16* qp = qkv + base + (size_t)(qb + l32) * D3 + h * 64 + hi * 8;
            #pragma unroll
            for (int kk = 0; kk < 4; ++kk)
                qf[kk] = *(const s16x8*)(qp + kk * 16);

            size_t kc0 = (size_t)c0 * 64 * D3;
            gld_lds16(kbase + kc0 + koff0, &Kl[0][w * 512]);
            gld_lds16(kbase + kc0 + koff1, &Kl[0][2048 + w * 512]);
            {
                const u16* vp = vbase + (size_t)(c0 * 64 + l) * D3;
                s16x8 pv0 = *(const s16x8*)vp;
                s16x8 pv1 = *(const s16x8*)(vp + 8);
                #pragma unroll
                for (int e = 0; e < 8; ++e) {
                    int d0 = w * 16 + e, d1 = w * 16 + 8 + e;
                    Vt[0][d0 * 64 + (l ^ ((d0 & 7) << 3))] = (u16)pv0[e];
                    Vt[0][d1 * 64 + (l ^ ((d1 & 7) << 3))] = (u16)pv1[e];
                }
            }
            __syncthreads();

            #pragma unroll 1
            for (int sc = c0; sc < c1; ++sc) {
                int cur = (sc - c0) & 1;
                bool pre = (sc + 1 < c1);
                s16x8 v0, v1;
                if (pre) {
                    size_t koffc = (size_t)(sc + 1) * 64 * D3;
                    gld_lds16(kbase + koffc + koff0, &Kl[cur ^ 1][w * 512]);
                    gld_lds16(kbase + koffc + koff1, &Kl[cur ^ 1][2048 + w * 512]);
                    const u16* vp = vbase + (size_t)((sc + 1) * 64 + l) * D3;
                    v0 = *(const s16x8*)vp;
                    v1 = *(const s16x8*)(vp + 8);
                }

                int kvb = sc * 64;
                int navail = ((qb - kvb) >> 5) + 1;
                if (navail > 0) {
                    if (navail > 2) navail = 2;
                    const u16* Kc = Kl[cur];
                    const u16* Vc = Vt[cur];
                    f32x16 sa0 = {}, sa1 = {};
                    #pragma unroll
                    for (int kk = 0; kk < 4; ++kk) {
                        s16x8 kf = *(const s16x8*)&Kc[l32 * 64 + (((2 * kk + hi) ^ xg) * 8)];
                        sa0 = mfma32(kf, qf[kk], sa0);
                    }
                    if (navail == 2) {
                        #pragma unroll
                        for (int kk = 0; kk < 4; ++kk) {
                            s16x8 kf = *(const s16x8*)&Kc[(32 + l32) * 64 + (((2 * kk + hi) ^ xg) * 8)];
                            sa1 = mfma32(kf, qf[kk], sa1);
                        }
                    }
                    bool diag0 = (kvb == qb);
                    bool diag1 = (kvb + 32 == qb);
                    float p[32];
                    float mx = -1e30f;
                    #pragma unroll
                    for (int reg = 0; reg < 16; ++reg) {
                        int kvloc = (reg & 3) + 8 * (reg >> 2) + 4 * hi;
                        float s0 = sa0[reg];
                        if (diag0 && kvloc > l32) s0 = -1e30f;
                        p[reg] = s0;
                        mx = fmaxf(mx, s0);
                    }
                    if (navail == 2) {
                        #pragma unroll
                        for (int reg = 0; reg < 16; ++reg) {
                            int kvloc = (reg & 3) + 8 * (reg >> 2) + 4 * hi;
                            float s1 = sa1[reg];
                            if (diag1 && kvloc > l32) s1 = -1e30f;
                            p[16 + reg] = s1;
                            mx = fmaxf(mx, s1);
                        }
                    }
                    mx = fmaxf(mx, __shfl_xor(mx, 32));
                    if (!__all(mx <= m + THR)) {          // defer-max (T13)
                        float mn = fmaxf(m, mx);
                        float a_ = exp2f(cexp * (m - mn));
                        m = mn;
                        #pragma unroll
                        for (int reg = 0; reg < 16; ++reg) {
                            int src = (reg & 3) + 8 * (reg >> 2) + 4 * hi;
                            float aq = __shfl(a_, src);
                            O0[reg] *= aq;
                            O1[reg] *= aq;
                        }
                        lr *= a_;
                    }
                    float rs = 0.f;
                    #pragma unroll
                    for (int reg = 0; reg < 16; ++reg) {
                        p[reg] = exp2f(cexp * (p[reg] - m));
                        rs += p[reg];
                    }
                    if (navail == 2) {
                        #pragma unroll
                        for (int reg = 16; reg < 32; ++reg) {
                            p[reg] = exp2f(cexp * (p[reg] - m));
                            rs += p[reg];
                        }
                    }
                    rs += __shfl_xor(rs, 32);
                    lr += rs;

                    #pragma unroll
                    for (int c = 0; c < 4; ++c) {
                        if (c < navail * 2) {
                            int pb = (c >> 1) * 16 + (c & 1) * 8;
                            int pk01 = cvtpk(p[pb + 0], p[pb + 1]);
                            int pk23 = cvtpk(p[pb + 2], p[pb + 3]);
                            int pk45 = cvtpk(p[pb + 4], p[pb + 5]);
                            int pk67 = cvtpk(p[pb + 6], p[pb + 7]);
                            int sx01 = __shfl_xor(pk01, 32);
                            int sx23 = __shfl_xor(pk23, 32);
                            int sx45 = __shfl_xor(pk45, 32);
                            int sx67 = __shfl_xor(pk67, 32);
                            union { int i[4]; s16x8 v; } u;
                            u.i[0] = hi ? sx45 : pk01;
                            u.i[1] = hi ? sx67 : pk23;
                            u.i[2] = hi ? pk45 : sx01;
                            u.i[3] = hi ? pk67 : sx23;
                            int go = ((c * 2 + hi) ^ xg) * 8;
                            s16x8 vb0 = *(const s16x8*)&Vc[l32 * 64 + go];
                            O0 = mfma32(u.v, vb0, O0);
                            s16x8 vb1 = *(const s16x8*)&Vc[(32 + l32) * 64 + go];
                            O1 = mfma32(u.v, vb1, O1);
                        }
                    }
                }

                if (pre) {
                    #pragma unroll
                    for (int e = 0; e < 8; ++e) {
                        int d0 = w * 16 + e, d1 = w * 16 + 8 + e;
                        Vt[cur ^ 1][d0 * 64 + (l ^ ((d0 & 7) << 3))] = (u16)v0[e];
                        Vt[cur ^ 1][d1 * 64 + (l ^ ((d1 & 7) << 3))] = (u16)v1[e];
                    }
                }
                __syncthreads();
            }
        }

        size_t obase = (size_t)b * S * 1024 + h * 64;
        #pragma unroll
        for (int reg = 0; reg < 16; ++reg) {
            int src = (reg & 3) + 8 * (reg >> 2) + 4 * hi;
            size_t row = obase + (size_t)(qb + src) * 1024;
            pout[row + l32] = f2b(O0[reg]);
            pout[row + 32 + l32] = f2b(O1[reg]);
        }
        if (hi == 0) {
            float2 st; st.x = m; st.y = lr;
            stats[third * 65536 + ((b * 2048 + qb + l32) * 16 + h)] = st;
        }
    }
}

// ------------------------- attention partial merge --------------------------
__global__ __launch_bounds__(256) void merge_attn(u16* __restrict__ p0,
                                                  const u16* __restrict__ p1,
                                                  const u16* __restrict__ p2,
                                                  const float2* __restrict__ stats) {
    constexpr float cexp = 0.18033688011112042f;
    int gid = blockIdx.x * 256 + threadIdx.x;    // [0, 65536*4)
    int rh = gid >> 2;
    int dc = (gid & 3) * 16;
    int R = rh >> 4, h = rh & 15;
    size_t addr = (size_t)R * 1024 + h * 64 + dc;

    float2 s0 = stats[rh];
    float2 s1 = stats[65536 + rh];
    float2 s2 = stats[131072 + rh];
    float M = fmaxf(s0.x, fmaxf(s1.x, s2.x));
    float a0 = exp2f(cexp * (s0.x - M));
    float a1 = exp2f(cexp * (s1.x - M));
    float a2 = exp2f(cexp * (s2.x - M));
    float inv = 1.f / (a0 * s0.y + a1 * s1.y + a2 * s2.y);
    a0 *= inv; a1 *= inv; a2 *= inv;

    u16x4 o[4];
    #pragma unroll
    for (int j = 0; j < 4; ++j) {
        u16x4 q0 = *(const u16x4*)(p0 + addr + j * 4);
        u16x4 q1 = *(const u16x4*)(p1 + addr + j * 4);
        u16x4 q2 = *(const u16x4*)(p2 + addr + j * 4);
        #pragma unroll
        for (int e = 0; e < 4; ++e)
            o[j][e] = f2b(a0 * b2f(q0[e]) + a1 * b2f(q1[e]) + a2 * b2f(q2[e]));
    }
    #pragma unroll
    for (int j = 0; j < 4; ++j)
        *(u16x4*)(p0 + addr + j * 4) = o[j];
}

// --------------------- residual + LayerNorm (row = 1024) --------------------
template<bool WB>
__global__ __launch_bounds__(256) void resln(const float* __restrict__ xa,
                                             const float* __restrict__ xb2,
                                             const float* __restrict__ g,
                                             const float* __restrict__ be,
                                             float* __restrict__ outf,
                                             u16* __restrict__ outb) {
    int row = blockIdx.x;
    int t = threadIdx.x;
    size_t base = (size_t)row * 1024 + t * 4;
    float4 va = *(const float4*)(xa + base);
    float4 vb = *(const float4*)(xb2 + base);
    float v0 = va.x + vb.x, v1 = va.y + vb.y, v2 = va.z + vb.z, v3 = va.w + vb.w;
    float s1 = v0 + v1 + v2 + v3;
    float s2 = v0 * v0 + v1 * v1 + v2 * v2 + v3 * v3;
    #pragma unroll
    for (int off = 32; off >= 1; off >>= 1) {
        s1 += __shfl_down(s1, off);
        s2 += __shfl_down(s2, off);
    }
    __shared__ float r1[4], r2[4];
    if ((t & 63) == 0) { r1[t >> 6] = s1; r2[t >> 6] = s2; }
    __syncthreads();
    s1 = r1[0] + r1[1] + r1[2] + r1[3];
    s2 = r2[0] + r2[1] + r2[2] + r2[3];
    float mean = s1 * (1.f / 1024.f);
    float var = fmaxf((s2 - 1024.f * mean * mean) * (1.f / 1023.f), 0.f);
    float inv = 1.f / (sqrtf(var) + 1e-6f);
    int col = t * 4;
    float y0 = g[col + 0] * ((v0 - mean) * inv) + be[col + 0];
    float y1 = g[col + 1] * ((v1 - mean) * inv) + be[col + 1];
    float y2 = g[col + 2] * ((v2 - mean) * inv) + be[col + 2];
    float y3 = g[col + 3] * ((v3 - mean) * inv) + be[col + 3];
    float4 o = {y0, y1, y2, y3};
    *(float4*)(outf + base) = o;
    if constexpr (WB) {
        u16x4 ob = {f2b(y0), f2b(y1), f2b(y2), f2b(y3)};
        *(u16x4*)(outb + base) = ob;
    }
}

// ---------------------------------------------------------------------------
extern "C" void kernel_launch(void* const* d_in, const int* in_sizes, int n_in,
                              void* d_out, int out_size, void* d_ws, size_t ws_size,
                              hipStream_t stream) {
    (void)in_sizes; (void)n_in; (void)out_size; (void)ws_size;
    const float* x       = (const float*)d_in[0];
    const float* w_attn  = (const float*)d_in[1];
    const float* b_attn  = (const float*)d_in[2];
    const float* w_aproj = (const float*)d_in[3];
    const float* b_aproj = (const float*)d_in[4];
    const float* g1      = (const float*)d_in[5];
    const float* b1      = (const float*)d_in[6];
    const float* w_fc    = (const float*)d_in[7];
    const float* b_fc    = (const float*)d_in[8];
    const float* w_mproj = (const float*)d_in[9];
    const float* b_mproj = (const float*)d_in[10];
    const float* g2      = (const float*)d_in[11];
    const float* b2      = (const float*)d_in[12];
    float* out = (float*)d_out;

    constexpr int M = 4096;           // B*S
    constexpr int D = 1024;

    char* ws = (char*)d_ws;
    u16*   slotA = (u16*)ws;                         // 32 MiB: qkv -> h
    char*  pB    = ws + (32u << 20);                 //  8 MiB: xb -> attn part0/abuf -> nb
    char*  pC    = ws + (40u << 20);                 //  8 MiB: attn part1 -> wT
    char*  pD    = ws + (48u << 20);                 // 16 MiB: attn part2 -> aout -> mout
    char*  pE    = ws + (64u << 20);                 // 16 MiB: attn stats -> nbuf (fp32)

    u16*   xb    = (u16*)pB;
    u16*   wT    = (u16*)pC;
    u16*   qkv   = slotA;
    u16*   part0 = (u16*)pB;                         // becomes merged abuf
    u16*   part1 = (u16*)pC;
    u16*   part2 = (u16*)pD;
    float2* stat = (float2*)pE;
    u16*   abuf  = (u16*)pB;
    float* aout  = (float*)pD;
    float* nbuf  = (float*)pE;
    u16*   nb    = (u16*)pB;
    u16*   h     = slotA;
    float* mout  = (float*)pD;

    dim3 blk(256);

    cvt_bf16<<<dim3(4096), blk, 0, stream>>>(x, xb, M * D / 4);

    transpose_bf16<<<dim3(3072 / 32, 1024 / 32), blk, 0, stream>>>(w_attn, wT, 1024, 3072);
    gemm_db<128, false, u16><<<dim3((M / 128) * (3072 / 128)), blk, 0, stream>>>(
        xb, wT, b_attn, qkv, M, 3072, 1024, 3072);

    attn_kernel<<<dim3(768), blk, 0, stream>>>(qkv, part0, part1, part2, stat);
    merge_attn<<<dim3(1024), blk, 0, stream>>>(part0, part1, part2, stat);

    transpose_bf16<<<dim3(1024 / 32, 1024 / 32), blk, 0, stream>>>(w_aproj, wT, 1024, 1024);
    gemm_db<64, false, float><<<dim3((M / 128) * (1024 / 64)), blk, 0, stream>>>(
        abuf, wT, b_aproj, aout, M, 1024, 1024, 1024);

    resln<true><<<dim3(M), blk, 0, stream>>>(x, aout, g1, b1, nbuf, nb);

    transpose_bf16<<<dim3(4096 / 32, 1024 / 32), blk, 0, stream>>>(w_fc, wT, 1024, 4096);
    gemm_db<128, true, u16><<<dim3((M / 128) * (4096 / 128)), blk, 0, stream>>>(
        nb, wT, b_fc, h, M, 4096, 1024, 4096);

    transpose_bf16<<<dim3(1024 / 32, 4096 / 32), blk, 0, stream>>>(w_mproj, wT, 4096, 1024);
    gemm_db<64, false, float><<<dim3((M / 128) * (1024 / 64)), blk, 0, stream>>>(
        h, wT, b_mproj, mout, M, 1024, 4096, 1024);

    resln<false><<<dim3(M), blk, 0, stream>>>(nbuf, mout, g2, b2, out, nullptr);
}

// Round 12
// 294.192 us; speedup vs baseline: 1.0490x; 1.0219x over previous
//
#include <hip/hip_runtime.h>
#include <type_traits>

// ---------------------------------------------------------------------------
// GPT block forward: B=2, S=2048, D=1024, H=16, DH=64
// Round 12: attention kv-split x4 (grid 1024 = 4 blocks/CU) + softmax exp via
// fma(cexp,p,-cm) (saves 32 VALU/chunk/lane). 4-partial merge.
// GEMM (full-swizzle db) / LN unchanged from round 11.
// ---------------------------------------------------------------------------

typedef unsigned short u16;
typedef short s16x8 __attribute__((ext_vector_type(8)));
typedef unsigned short u16x4 __attribute__((ext_vector_type(4)));
typedef float f32x4 __attribute__((ext_vector_type(4)));
typedef float f32x16 __attribute__((ext_vector_type(16)));

__device__ __forceinline__ u16 f2b(float f) {
    union { float f; unsigned u; } x{f};
    unsigned r = x.u + 0x7FFFu + ((x.u >> 16) & 1u);  // RNE
    return (u16)(r >> 16);
}

__device__ __forceinline__ float b2f(u16 v) {
    union { unsigned u; float f; } x;
    x.u = ((unsigned)v) << 16;
    return x.f;
}

__device__ __forceinline__ f32x4 mfma16(s16x8 a, s16x8 b, f32x4 c) {
    return __builtin_amdgcn_mfma_f32_16x16x32_bf16(a, b, c, 0, 0, 0);
}

__device__ __forceinline__ f32x16 mfma32(s16x8 a, s16x8 b, f32x16 c) {
    return __builtin_amdgcn_mfma_f32_32x32x16_bf16(a, b, c, 0, 0, 0);
}

__device__ __forceinline__ int cvtpk(float a, float b) {
    int r;
    asm("v_cvt_pk_bf16_f32 %0, %1, %2" : "=v"(r) : "v"(a), "v"(b));
    return r;
}

__device__ __forceinline__ void gld_lds16(const u16* g, u16* l) {
    __builtin_amdgcn_global_load_lds(
        (const __attribute__((address_space(1))) void*)g,
        (__attribute__((address_space(3))) void*)l, 16, 0, 0);
}

// --------------------------- fp32 -> bf16 convert ---------------------------
__global__ __launch_bounds__(256) void cvt_bf16(const float* __restrict__ in,
                                                u16* __restrict__ out, int n4) {
    int i = blockIdx.x * 256 + threadIdx.x;
    if (i < n4) {
        float4 v = ((const float4*)in)[i];
        u16x4 o = {f2b(v.x), f2b(v.y), f2b(v.z), f2b(v.w)};
        ((u16x4*)out)[i] = o;
    }
}

// ------------------- transpose fp32 [K,N] -> bf16 [N,K] ---------------------
__global__ __launch_bounds__(256) void transpose_bf16(const float* __restrict__ W,
                                                      u16* __restrict__ WT,
                                                      int K, int N) {
    __shared__ float t[32][33];
    int tx = threadIdx.x & 31, ty = threadIdx.x >> 5;
    int n0 = blockIdx.x * 32, k0 = blockIdx.y * 32;
    #pragma unroll
    for (int r = ty; r < 32; r += 8)
        t[r][tx] = W[(size_t)(k0 + r) * N + n0 + tx];
    __syncthreads();
    #pragma unroll
    for (int r = ty; r < 32; r += 8)
        WT[(size_t)(n0 + r) * K + k0 + tx] = f2b(t[tx][r]);
}

// ------------------ MFMA GEMM, 2-phase double-buffered ----------------------
// Round-11 verified: BM=128, BK=64, full row&7 granule-XOR swizzle (0 bank
// conflicts), loads for tile k+1 in flight across the single barrier.
template<int BN, bool GELU, typename OT>
__global__ __launch_bounds__(256) void gemm_db(const u16* __restrict__ A,
                                               const u16* __restrict__ BT,
                                               const float* __restrict__ bias,
                                               OT* __restrict__ C,
                                               int M, int N, int K, int ldc) {
    constexpr int NF = BN / 32;
    constexpr int BNI = BN / 32;
    __shared__ u16 As[2][128 * 64];
    __shared__ u16 Bs[2][BN * 64];

    int t = threadIdx.x;
    int w = t >> 6, l = t & 63, l16 = l & 15, lh = l >> 4;
    int wr = w >> 1, wc = w & 1;

    int nbm = M >> 7;
    int cpx = gridDim.x >> 3;
    int id = blockIdx.x;
    int id2 = (id & 7) * cpx + (id >> 3);
    size_t m0 = (size_t)(id2 % nbm) * 128;
    size_t n0 = (size_t)(id2 / nbm) * BN;

    int rowA = t >> 3;
    int gc2 = (t & 7) ^ (rowA & 7);
    const u16* Ag = A + (m0 + rowA) * (size_t)K + gc2 * 8;
    const u16* Bg = BT + (n0 + rowA) * (size_t)K + gc2 * 8;
    int wbase = w * 512;

    f32x4 acc[4][NF] = {};
    int rx = (l16 & 7) * 8;

    #pragma unroll
    for (int j = 0; j < 4; ++j)
        gld_lds16(Ag + (size_t)j * 32 * K, &As[0][j * 2048 + wbase]);
    #pragma unroll
    for (int j = 0; j < BNI; ++j)
        gld_lds16(Bg + (size_t)j * 32 * K, &Bs[0][j * 2048 + wbase]);
    __syncthreads();

    int cur = 0;
    for (int k0 = 0; k0 < K; k0 += 64) {
        if (k0 + 64 < K) {
            const u16* Ap = Ag + k0 + 64;
            #pragma unroll
            for (int j = 0; j < 4; ++j)
                gld_lds16(Ap + (size_t)j * 32 * K, &As[cur ^ 1][j * 2048 + wbase]);
            const u16* Bp = Bg + k0 + 64;
            #pragma unroll
            for (int j = 0; j < BNI; ++j)
                gld_lds16(Bp + (size_t)j * 32 * K, &Bs[cur ^ 1][j * 2048 + wbase]);
        }
        __builtin_amdgcn_s_setprio(1);
        #pragma unroll
        for (int ks = 0; ks < 2; ++ks) {
            s16x8 af[4], bf[NF];
            #pragma unroll
            for (int fm = 0; fm < 4; ++fm) {
                int row = wr * 64 + fm * 16 + l16;
                int col = ((ks * 4 + lh) * 8) ^ rx;
                af[fm] = *(const s16x8*)&As[cur][row * 64 + col];
            }
            #pragma unroll
            for (int fn = 0; fn < NF; ++fn) {
                int row = wc * (BN / 2) + fn * 16 + l16;
                int col = ((ks * 4 + lh) * 8) ^ rx;
                bf[fn] = *(const s16x8*)&Bs[cur][row * 64 + col];
            }
            #pragma unroll
            for (int fm = 0; fm < 4; ++fm)
                #pragma unroll
                for (int fn = 0; fn < NF; ++fn)
                    acc[fm][fn] = mfma16(af[fm], bf[fn], acc[fm][fn]);
        }
        __builtin_amdgcn_s_setprio(0);
        __syncthreads();
        cur ^= 1;
    }

    #pragma unroll
    for (int fn = 0; fn < NF; ++fn) {
        size_t col = n0 + wc * (BN / 2) + fn * 16 + l16;
        float bs = bias[col];
        #pragma unroll
        for (int fm = 0; fm < 4; ++fm) {
            size_t row0 = m0 + wr * 64 + fm * 16 + lh * 4;
            #pragma unroll
            for (int i = 0; i < 4; ++i) {
                float v = acc[fm][fn][i] + bs;
                if constexpr (GELU) {
                    float x3 = v * v * v;
                    v = 0.5f * v * (1.f + tanhf(0.7978845608f * (v + 0.044715f * x3)));
                }
                if constexpr (std::is_same<OT, u16>::value)
                    C[(row0 + i) * ldc + col] = f2b(v);
                else
                    C[(row0 + i) * ldc + col] = v;
            }
        }
    }
}

// --------------------------- causal attention -------------------------------
// kv-split x4: block = (quarter, pair pr, bh). Each writes unnormalized O
// partial + (m,lr) stats. exp via fma(cexp,p,-cm). Pipeline = round 9/11.
__global__ __launch_bounds__(256) void attn_kernel(const u16* __restrict__ qkv,
                                                   u16* __restrict__ p0,
                                                   u16* __restrict__ p1,
                                                   u16* __restrict__ p2,
                                                   u16* __restrict__ p3,
                                                   float2* __restrict__ stats) {
    constexpr int S = 2048, D3 = 3072, Dm = 1024;
    __shared__ u16 Kl[2][64 * 64];
    __shared__ u16 Vt[2][64 * 64];

    int t = threadIdx.x;
    int w = t >> 6, l = t & 63;
    int l32 = l & 31, hi = l >> 5;
    int bid = blockIdx.x;
    int bh = bid & 31;
    int pr = (bid >> 5) & 7;
    int quar = bid >> 8;                // 0..3
    int b = bh >> 4, h = bh & 15;
    size_t base = (size_t)b * S * D3;

    u16* pout = quar == 0 ? p0 : (quar == 1 ? p1 : (quar == 2 ? p2 : p3));

    int rK0 = t >> 3, gK = t & 7;
    int rK1 = rK0 + 32;
    size_t koff0 = (size_t)rK0 * D3 + (size_t)((gK ^ (rK0 & 7)) * 8);
    size_t koff1 = (size_t)rK1 * D3 + (size_t)((gK ^ (rK1 & 7)) * 8);
    const u16* kbase = qkv + base + Dm + h * 64;
    const u16* vbase = qkv + base + 2 * Dm + h * 64 + w * 16;

    constexpr float cexp = 0.18033688011112042f;   // 0.125 * log2(e)
    constexpr float THR = 64.0f;                    // defer-max threshold
    int xg = l32 & 7;

    #pragma unroll 1
    for (int ph = 0; ph < 2; ++ph) {
        int qt = ph ? (15 - pr) : pr;
        int qb = qt * 128 + w * 32;
        int nst = 2 * (qt + 1);
        int c0 = (nst * quar) >> 2;
        int c1 = (nst * (quar + 1)) >> 2;

        f32x16 O0 = {}, O1 = {};
        float m = -1e30f, lr = 0.f;

        if (c0 < c1) {
            s16x8 qf[4];
            const u16* qp = qkv + base + (size_t)(qb + l32) * D3 + h * 64 + hi * 8;
            #pragma unroll
            for (int kk = 0; kk < 4; ++kk)
                qf[kk] = *(const s16x8*)(qp + kk * 16);

            size_t kc0 = (size_t)c0 * 64 * D3;
            gld_lds16(kbase + kc0 + koff0, &Kl[0][w * 512]);
            gld_lds16(kbase + kc0 + koff1, &Kl[0][2048 + w * 512]);
            {
                const u16* vp = vbase + (size_t)(c0 * 64 + l) * D3;
                s16x8 pv0 = *(const s16x8*)vp;
                s16x8 pv1 = *(const s16x8*)(vp + 8);
                #pragma unroll
                for (int e = 0; e < 8; ++e) {
                    int d0 = w * 16 + e, d1 = w * 16 + 8 + e;
                    Vt[0][d0 * 64 + (l ^ ((d0 & 7) << 3))] = (u16)pv0[e];
                    Vt[0][d1 * 64 + (l ^ ((d1 & 7) << 3))] = (u16)pv1[e];
                }
            }
            __syncthreads();

            #pragma unroll 1
            for (int sc = c0; sc < c1; ++sc) {
                int cur = (sc - c0) & 1;
                bool pre = (sc + 1 < c1);
                s16x8 v0, v1;
                if (pre) {
                    size_t koffc = (size_t)(sc + 1) * 64 * D3;
                    gld_lds16(kbase + koffc + koff0, &Kl[cur ^ 1][w * 512]);
                    gld_lds16(kbase + koffc + koff1, &Kl[cur ^ 1][2048 + w * 512]);
                    const u16* vp = vbase + (size_t)((sc + 1) * 64 + l) * D3;
                    v0 = *(const s16x8*)vp;
                    v1 = *(const s16x8*)(vp + 8);
                }

                int kvb = sc * 64;
                int navail = ((qb - kvb) >> 5) + 1;
                if (navail > 0) {
                    if (navail > 2) navail = 2;
                    const u16* Kc = Kl[cur];
                    const u16* Vc = Vt[cur];
                    f32x16 sa0 = {}, sa1 = {};
                    #pragma unroll
                    for (int kk = 0; kk < 4; ++kk) {
                        s16x8 kf = *(const s16x8*)&Kc[l32 * 64 + (((2 * kk + hi) ^ xg) * 8)];
                        sa0 = mfma32(kf, qf[kk], sa0);
                    }
                    if (navail == 2) {
                        #pragma unroll
                        for (int kk = 0; kk < 4; ++kk) {
                            s16x8 kf = *(const s16x8*)&Kc[(32 + l32) * 64 + (((2 * kk + hi) ^ xg) * 8)];
                            sa1 = mfma32(kf, qf[kk], sa1);
                        }
                    }
                    bool diag0 = (kvb == qb);
                    bool diag1 = (kvb + 32 == qb);
                    float p[32];
                    float mx = -1e30f;
                    #pragma unroll
                    for (int reg = 0; reg < 16; ++reg) {
                        int kvloc = (reg & 3) + 8 * (reg >> 2) + 4 * hi;
                        float s0 = sa0[reg];
                        if (diag0 && kvloc > l32) s0 = -1e30f;
                        p[reg] = s0;
                        mx = fmaxf(mx, s0);
                    }
                    if (navail == 2) {
                        #pragma unroll
                        for (int reg = 0; reg < 16; ++reg) {
                            int kvloc = (reg & 3) + 8 * (reg >> 2) + 4 * hi;
                            float s1 = sa1[reg];
                            if (diag1 && kvloc > l32) s1 = -1e30f;
                            p[16 + reg] = s1;
                            mx = fmaxf(mx, s1);
                        }
                    }
                    mx = fmaxf(mx, __shfl_xor(mx, 32));
                    if (!__all(mx <= m + THR)) {          // defer-max (T13)
                        float mn = fmaxf(m, mx);
                        float a_ = exp2f(cexp * (m - mn));
                        m = mn;
                        #pragma unroll
                        for (int reg = 0; reg < 16; ++reg) {
                            int src = (reg & 3) + 8 * (reg >> 2) + 4 * hi;
                            float aq = __shfl(a_, src);
                            O0[reg] *= aq;
                            O1[reg] *= aq;
                        }
                        lr *= a_;
                    }
                    float cm = cexp * m;                  // exp2(cexp*p - cm)
                    float rs = 0.f;
                    #pragma unroll
                    for (int reg = 0; reg < 16; ++reg) {
                        p[reg] = exp2f(fmaf(cexp, p[reg], -cm));
                        rs += p[reg];
                    }
                    if (navail == 2) {
                        #pragma unroll
                        for (int reg = 16; reg < 32; ++reg) {
                            p[reg] = exp2f(fmaf(cexp, p[reg], -cm));
                            rs += p[reg];
                        }
                    }
                    rs += __shfl_xor(rs, 32);
                    lr += rs;

                    #pragma unroll
                    for (int c = 0; c < 4; ++c) {
                        if (c < navail * 2) {
                            int pb = (c >> 1) * 16 + (c & 1) * 8;
                            int pk01 = cvtpk(p[pb + 0], p[pb + 1]);
                            int pk23 = cvtpk(p[pb + 2], p[pb + 3]);
                            int pk45 = cvtpk(p[pb + 4], p[pb + 5]);
                            int pk67 = cvtpk(p[pb + 6], p[pb + 7]);
                            int sx01 = __shfl_xor(pk01, 32);
                            int sx23 = __shfl_xor(pk23, 32);
                            int sx45 = __shfl_xor(pk45, 32);
                            int sx67 = __shfl_xor(pk67, 32);
                            union { int i[4]; s16x8 v; } u;
                            u.i[0] = hi ? sx45 : pk01;
                            u.i[1] = hi ? sx67 : pk23;
                            u.i[2] = hi ? pk45 : sx01;
                            u.i[3] = hi ? pk67 : sx23;
                            int go = ((c * 2 + hi) ^ xg) * 8;
                            s16x8 vb0 = *(const s16x8*)&Vc[l32 * 64 + go];
                            O0 = mfma32(u.v, vb0, O0);
                            s16x8 vb1 = *(const s16x8*)&Vc[(32 + l32) * 64 + go];
                            O1 = mfma32(u.v, vb1, O1);
                        }
                    }
                }

                if (pre) {
                    #pragma unroll
                    for (int e = 0; e < 8; ++e) {
                        int d0 = w * 16 + e, d1 = w * 16 + 8 + e;
                        Vt[cur ^ 1][d0 * 64 + (l ^ ((d0 & 7) << 3))] = (u16)v0[e];
                        Vt[cur ^ 1][d1 * 64 + (l ^ ((d1 & 7) << 3))] = (u16)v1[e];
                    }
                }
                __syncthreads();
            }
        }

        size_t obase = (size_t)b * S * 1024 + h * 64;
        #pragma unroll
        for (int reg = 0; reg < 16; ++reg) {
            int src = (reg & 3) + 8 * (reg >> 2) + 4 * hi;
            size_t row = obase + (size_t)(qb + src) * 1024;
            pout[row + l32] = f2b(O0[reg]);
            pout[row + 32 + l32] = f2b(O1[reg]);
        }
        if (hi == 0) {
            float2 st; st.x = m; st.y = lr;
            stats[quar * 65536 + ((b * 2048 + qb + l32) * 16 + h)] = st;
        }
    }
}

// ------------------------- attention partial merge (x4) ---------------------
__global__ __launch_bounds__(256) void merge_attn(u16* __restrict__ p0,
                                                  const u16* __restrict__ p1,
                                                  const u16* __restrict__ p2,
                                                  const u16* __restrict__ p3,
                                                  const float2* __restrict__ stats) {
    constexpr float cexp = 0.18033688011112042f;
    int gid = blockIdx.x * 256 + threadIdx.x;    // [0, 65536*4)
    int rh = gid >> 2;
    int dc = (gid & 3) * 16;
    int R = rh >> 4, h = rh & 15;
    size_t addr = (size_t)R * 1024 + h * 64 + dc;

    float2 s0 = stats[rh];
    float2 s1 = stats[65536 + rh];
    float2 s2 = stats[131072 + rh];
    float2 s3 = stats[196608 + rh];
    float M = fmaxf(fmaxf(s0.x, s1.x), fmaxf(s2.x, s3.x));
    float a0 = exp2f(cexp * (s0.x - M));
    float a1 = exp2f(cexp * (s1.x - M));
    float a2 = exp2f(cexp * (s2.x - M));
    float a3 = exp2f(cexp * (s3.x - M));
    float inv = 1.f / (a0 * s0.y + a1 * s1.y + a2 * s2.y + a3 * s3.y);
    a0 *= inv; a1 *= inv; a2 *= inv; a3 *= inv;

    u16x4 o[4];
    #pragma unroll
    for (int j = 0; j < 4; ++j) {
        u16x4 q0 = *(const u16x4*)(p0 + addr + j * 4);
        u16x4 q1 = *(const u16x4*)(p1 + addr + j * 4);
        u16x4 q2 = *(const u16x4*)(p2 + addr + j * 4);
        u16x4 q3 = *(const u16x4*)(p3 + addr + j * 4);
        #pragma unroll
        for (int e = 0; e < 4; ++e)
            o[j][e] = f2b(a0 * b2f(q0[e]) + a1 * b2f(q1[e]) +
                          a2 * b2f(q2[e]) + a3 * b2f(q3[e]));
    }
    #pragma unroll
    for (int j = 0; j < 4; ++j)
        *(u16x4*)(p0 + addr + j * 4) = o[j];
}

// --------------------- residual + LayerNorm (row = 1024) --------------------
template<bool WB>
__global__ __launch_bounds__(256) void resln(const float* __restrict__ xa,
                                             const float* __restrict__ xb2,
                                             const float* __restrict__ g,
                                             const float* __restrict__ be,
                                             float* __restrict__ outf,
                                             u16* __restrict__ outb) {
    int row = blockIdx.x;
    int t = threadIdx.x;
    size_t base = (size_t)row * 1024 + t * 4;
    float4 va = *(const float4*)(xa + base);
    float4 vb = *(const float4*)(xb2 + base);
    float v0 = va.x + vb.x, v1 = va.y + vb.y, v2 = va.z + vb.z, v3 = va.w + vb.w;
    float s1 = v0 + v1 + v2 + v3;
    float s2 = v0 * v0 + v1 * v1 + v2 * v2 + v3 * v3;
    #pragma unroll
    for (int off = 32; off >= 1; off >>= 1) {
        s1 += __shfl_down(s1, off);
        s2 += __shfl_down(s2, off);
    }
    __shared__ float r1[4], r2[4];
    if ((t & 63) == 0) { r1[t >> 6] = s1; r2[t >> 6] = s2; }
    __syncthreads();
    s1 = r1[0] + r1[1] + r1[2] + r1[3];
    s2 = r2[0] + r2[1] + r2[2] + r2[3];
    float mean = s1 * (1.f / 1024.f);
    float var = fmaxf((s2 - 1024.f * mean * mean) * (1.f / 1023.f), 0.f);
    float inv = 1.f / (sqrtf(var) + 1e-6f);
    int col = t * 4;
    float y0 = g[col + 0] * ((v0 - mean) * inv) + be[col + 0];
    float y1 = g[col + 1] * ((v1 - mean) * inv) + be[col + 1];
    float y2 = g[col + 2] * ((v2 - mean) * inv) + be[col + 2];
    float y3 = g[col + 3] * ((v3 - mean) * inv) + be[col + 3];
    float4 o = {y0, y1, y2, y3};
    *(float4*)(outf + base) = o;
    if constexpr (WB) {
        u16x4 ob = {f2b(y0), f2b(y1), f2b(y2), f2b(y3)};
        *(u16x4*)(outb + base) = ob;
    }
}

// ---------------------------------------------------------------------------
extern "C" void kernel_launch(void* const* d_in, const int* in_sizes, int n_in,
                              void* d_out, int out_size, void* d_ws, size_t ws_size,
                              hipStream_t stream) {
    (void)in_sizes; (void)n_in; (void)out_size; (void)ws_size;
    const float* x       = (const float*)d_in[0];
    const float* w_attn  = (const float*)d_in[1];
    const float* b_attn  = (const float*)d_in[2];
    const float* w_aproj = (const float*)d_in[3];
    const float* b_aproj = (const float*)d_in[4];
    const float* g1      = (const float*)d_in[5];
    const float* b1      = (const float*)d_in[6];
    const float* w_fc    = (const float*)d_in[7];
    const float* b_fc    = (const float*)d_in[8];
    const float* w_mproj = (const float*)d_in[9];
    const float* b_mproj = (const float*)d_in[10];
    const float* g2      = (const float*)d_in[11];
    const float* b2      = (const float*)d_in[12];
    float* out = (float*)d_out;

    constexpr int M = 4096;           // B*S
    constexpr int D = 1024;

    char* ws = (char*)d_ws;
    u16*   slotA = (u16*)ws;                         // 32 MiB: qkv -> h
    char*  pB    = ws + (32u << 20);                 //  8 MiB: xb -> part0/abuf -> nb
    char*  pC    = ws + (40u << 20);                 //  8 MiB: part1 -> wT
    char*  pD    = ws + (48u << 20);                 // 16 MiB: part2+part3 -> aout -> mout
    char*  pE    = ws + (64u << 20);                 // 16 MiB: stats -> nbuf (fp32)

    u16*   xb    = (u16*)pB;
    u16*   wT    = (u16*)pC;
    u16*   qkv   = slotA;
    u16*   part0 = (u16*)pB;                         // becomes merged abuf
    u16*   part1 = (u16*)pC;
    u16*   part2 = (u16*)pD;
    u16*   part3 = (u16*)(pD + (8u << 20));
    float2* stat = (float2*)pE;
    u16*   abuf  = (u16*)pB;
    float* aout  = (float*)pD;
    float* nbuf  = (float*)pE;
    u16*   nb    = (u16*)pB;
    u16*   h     = slotA;
    float* mout  = (float*)pD;

    dim3 blk(256);

    cvt_bf16<<<dim3(4096), blk, 0, stream>>>(x, xb, M * D / 4);

    transpose_bf16<<<dim3(3072 / 32, 1024 / 32), blk, 0, stream>>>(w_attn, wT, 1024, 3072);
    gemm_db<128, false, u16><<<dim3((M / 128) * (3072 / 128)), blk, 0, stream>>>(
        xb, wT, b_attn, qkv, M, 3072, 1024, 3072);

    attn_kernel<<<dim3(1024), blk, 0, stream>>>(qkv, part0, part1, part2, part3, stat);
    merge_attn<<<dim3(1024), blk, 0, stream>>>(part0, part1, part2, part3, stat);

    transpose_bf16<<<dim3(1024 / 32, 1024 / 32), blk, 0, stream>>>(w_aproj, wT, 1024, 1024);
    gemm_db<64, false, float><<<dim3((M / 128) * (1024 / 64)), blk, 0, stream>>>(
        abuf, wT, b_aproj, aout, M, 1024, 1024, 1024);

    resln<true><<<dim3(M), blk, 0, stream>>>(x, aout, g1, b1, nbuf, nb);

    transpose_bf16<<<dim3(4096 / 32, 1024 / 32), blk, 0, stream>>>(w_fc, wT, 1024, 4096);
    gemm_db<128, true, u16><<<dim3((M / 128) * (4096 / 128)), blk, 0, stream>>>(
        nb, wT, b_fc, h, M, 4096, 1024, 4096);

    transpose_bf16<<<dim3(1024 / 32, 4096 / 32), blk, 0, stream>>>(w_mproj, wT, 4096, 1024);
    gemm_db<64, false, float><<<dim3((M / 128) * (1024 / 64)), blk, 0, stream>>>(
        h, wT, b_mproj, mout, M, 1024, 4096, 1024);

    resln<false><<<dim3(M), blk, 0, stream>>>(nbuf, mout, g2, b2, out, nullptr);
}

// Round 13
// 284.973 us; speedup vs baseline: 1.0830x; 1.0324x over previous
//
#include <hip/hip_runtime.h>
#include <type_traits>

// ---------------------------------------------------------------------------
// GPT block forward: B=2, S=2048, D=1024, H=16, DH=64
// Round 13: GEMM -> 2-deep counted-vmcnt pipeline (T4): raw s_barrier (no
// vmcnt(0) drain), s_waitcnt vmcnt(L) keeps next tile's loads in flight.
// Addressing/swizzle identical to round-11/12 verified gemm_db.
// Attention (kv-split x4) / merge / LN unchanged from round 12.
// ---------------------------------------------------------------------------

typedef unsigned short u16;
typedef short s16x8 __attribute__((ext_vector_type(8)));
typedef unsigned short u16x4 __attribute__((ext_vector_type(4)));
typedef float f32x4 __attribute__((ext_vector_type(4)));
typedef float f32x16 __attribute__((ext_vector_type(16)));

__device__ __forceinline__ u16 f2b(float f) {
    union { float f; unsigned u; } x{f};
    unsigned r = x.u + 0x7FFFu + ((x.u >> 16) & 1u);  // RNE
    return (u16)(r >> 16);
}

__device__ __forceinline__ float b2f(u16 v) {
    union { unsigned u; float f; } x;
    x.u = ((unsigned)v) << 16;
    return x.f;
}

__device__ __forceinline__ f32x4 mfma16(s16x8 a, s16x8 b, f32x4 c) {
    return __builtin_amdgcn_mfma_f32_16x16x32_bf16(a, b, c, 0, 0, 0);
}

__device__ __forceinline__ f32x16 mfma32(s16x8 a, s16x8 b, f32x16 c) {
    return __builtin_amdgcn_mfma_f32_32x32x16_bf16(a, b, c, 0, 0, 0);
}

__device__ __forceinline__ int cvtpk(float a, float b) {
    int r;
    asm("v_cvt_pk_bf16_f32 %0, %1, %2" : "=v"(r) : "v"(a), "v"(b));
    return r;
}

__device__ __forceinline__ void gld_lds16(const u16* g, u16* l) {
    __builtin_amdgcn_global_load_lds(
        (const __attribute__((address_space(1))) void*)g,
        (__attribute__((address_space(3))) void*)l, 16, 0, 0);
}

__device__ __forceinline__ void hard_barrier() {
    __builtin_amdgcn_sched_barrier(0);
    __builtin_amdgcn_s_barrier();
    __builtin_amdgcn_sched_barrier(0);
}

// --------------------------- fp32 -> bf16 convert ---------------------------
__global__ __launch_bounds__(256) void cvt_bf16(const float* __restrict__ in,
                                                u16* __restrict__ out, int n4) {
    int i = blockIdx.x * 256 + threadIdx.x;
    if (i < n4) {
        float4 v = ((const float4*)in)[i];
        u16x4 o = {f2b(v.x), f2b(v.y), f2b(v.z), f2b(v.w)};
        ((u16x4*)out)[i] = o;
    }
}

// ------------------- transpose fp32 [K,N] -> bf16 [N,K] ---------------------
__global__ __launch_bounds__(256) void transpose_bf16(const float* __restrict__ W,
                                                      u16* __restrict__ WT,
                                                      int K, int N) {
    __shared__ float t[32][33];
    int tx = threadIdx.x & 31, ty = threadIdx.x >> 5;
    int n0 = blockIdx.x * 32, k0 = blockIdx.y * 32;
    #pragma unroll
    for (int r = ty; r < 32; r += 8)
        t[r][tx] = W[(size_t)(k0 + r) * N + n0 + tx];
    __syncthreads();
    #pragma unroll
    for (int r = ty; r < 32; r += 8)
        WT[(size_t)(n0 + r) * K + k0 + tx] = f2b(t[tx][r]);
}

// ------------- MFMA GEMM, 2-deep counted-vmcnt pipeline (T4) ----------------
// BM=128, BK=64, 4 waves (2x2), wave tile 64 x BN/2. Full row&7 granule-XOR
// swizzle (0 conflicts, validated r10/r11). Pipeline: tiles k and k+1 in
// flight; per iter wait vmcnt(L) = tile k only, raw s_barrier (no drain),
// compute, raw s_barrier, stage tile k+2 into the freed buffer.
template<int BN, bool GELU, typename OT>
__global__ __launch_bounds__(256) void gemm_pl(const u16* __restrict__ A,
                                               const u16* __restrict__ BT,
                                               const float* __restrict__ bias,
                                               OT* __restrict__ C,
                                               int M, int N, int K, int ldc) {
    constexpr int NF = BN / 32;
    constexpr int BNI = BN / 32;          // B loads per thread per tile
    __shared__ u16 As[2][128 * 64];
    __shared__ u16 Bs[2][BN * 64];

    int t = threadIdx.x;
    int w = t >> 6, l = t & 63, l16 = l & 15, lh = l >> 4;
    int wr = w >> 1, wc = w & 1;

    int nbm = M >> 7;
    int cpx = gridDim.x >> 3;
    int id = blockIdx.x;
    int id2 = (id & 7) * cpx + (id >> 3);
    size_t m0 = (size_t)(id2 % nbm) * 128;
    size_t n0 = (size_t)(id2 / nbm) * BN;

    int rowA = t >> 3;
    int gc2 = (t & 7) ^ (rowA & 7);
    const u16* Ag = A + (m0 + rowA) * (size_t)K + gc2 * 8;
    const u16* Bg = BT + (n0 + rowA) * (size_t)K + gc2 * 8;
    int wbase = w * 512;

    f32x4 acc[4][NF] = {};
    int rx = (l16 & 7) * 8;

    // prologue: tile 0 -> buf0, tile 1 -> buf1
    #pragma unroll
    for (int j = 0; j < 4; ++j)
        gld_lds16(Ag + (size_t)j * 32 * K, &As[0][j * 2048 + wbase]);
    #pragma unroll
    for (int j = 0; j < BNI; ++j)
        gld_lds16(Bg + (size_t)j * 32 * K, &Bs[0][j * 2048 + wbase]);
    if (K > 64) {
        #pragma unroll
        for (int j = 0; j < 4; ++j)
            gld_lds16(Ag + 64 + (size_t)j * 32 * K, &As[1][j * 2048 + wbase]);
        #pragma unroll
        for (int j = 0; j < BNI; ++j)
            gld_lds16(Bg + 64 + (size_t)j * 32 * K, &Bs[1][j * 2048 + wbase]);
    }

    int cur = 0;
    for (int k0 = 0; k0 < K; k0 += 64) {
        // wait for tile k only; keep tile k+1's L loads in flight
        if (k0 + 64 >= K)
            asm volatile("s_waitcnt vmcnt(0)" ::: "memory");
        else if constexpr (BNI == 4)
            asm volatile("s_waitcnt vmcnt(8)" ::: "memory");
        else
            asm volatile("s_waitcnt vmcnt(6)" ::: "memory");
        hard_barrier();                  // all waves' tile-k loads landed

        __builtin_amdgcn_s_setprio(1);
        #pragma unroll
        for (int ks = 0; ks < 2; ++ks) {
            s16x8 af[4], bf[NF];
            #pragma unroll
            for (int fm = 0; fm < 4; ++fm) {
                int row = wr * 64 + fm * 16 + l16;
                int col = ((ks * 4 + lh) * 8) ^ rx;
                af[fm] = *(const s16x8*)&As[cur][row * 64 + col];
            }
            #pragma unroll
            for (int fn = 0; fn < NF; ++fn) {
                int row = wc * (BN / 2) + fn * 16 + l16;
                int col = ((ks * 4 + lh) * 8) ^ rx;
                bf[fn] = *(const s16x8*)&Bs[cur][row * 64 + col];
            }
            #pragma unroll
            for (int fm = 0; fm < 4; ++fm)
                #pragma unroll
                for (int fn = 0; fn < NF; ++fn)
                    acc[fm][fn] = mfma16(af[fm], bf[fn], acc[fm][fn]);
        }
        __builtin_amdgcn_s_setprio(0);
        hard_barrier();                  // all waves done reading buf[cur]

        if (k0 + 128 < K) {              // stage tile k+2 into freed buffer
            const u16* Ap = Ag + k0 + 128;
            #pragma unroll
            for (int j = 0; j < 4; ++j)
                gld_lds16(Ap + (size_t)j * 32 * K, &As[cur][j * 2048 + wbase]);
            const u16* Bp = Bg + k0 + 128;
            #pragma unroll
            for (int j = 0; j < BNI; ++j)
                gld_lds16(Bp + (size_t)j * 32 * K, &Bs[cur][j * 2048 + wbase]);
        }
        cur ^= 1;
    }

    #pragma unroll
    for (int fn = 0; fn < NF; ++fn) {
        size_t col = n0 + wc * (BN / 2) + fn * 16 + l16;
        float bs = bias[col];
        #pragma unroll
        for (int fm = 0; fm < 4; ++fm) {
            size_t row0 = m0 + wr * 64 + fm * 16 + lh * 4;
            #pragma unroll
            for (int i = 0; i < 4; ++i) {
                float v = acc[fm][fn][i] + bs;
                if constexpr (GELU) {
                    float x3 = v * v * v;
                    v = 0.5f * v * (1.f + tanhf(0.7978845608f * (v + 0.044715f * x3)));
                }
                if constexpr (std::is_same<OT, u16>::value)
                    C[(row0 + i) * ldc + col] = f2b(v);
                else
                    C[(row0 + i) * ldc + col] = v;
            }
        }
    }
}

// --------------------------- causal attention -------------------------------
// kv-split x4 (round 12, verified): block = (quarter, pair pr, bh).
__global__ __launch_bounds__(256) void attn_kernel(const u16* __restrict__ qkv,
                                                   u16* __restrict__ p0,
                                                   u16* __restrict__ p1,
                                                   u16* __restrict__ p2,
                                                   u16* __restrict__ p3,
                                                   float2* __restrict__ stats) {
    constexpr int S = 2048, D3 = 3072, Dm = 1024;
    __shared__ u16 Kl[2][64 * 64];
    __shared__ u16 Vt[2][64 * 64];

    int t = threadIdx.x;
    int w = t >> 6, l = t & 63;
    int l32 = l & 31, hi = l >> 5;
    int bid = blockIdx.x;
    int bh = bid & 31;
    int pr = (bid >> 5) & 7;
    int quar = bid >> 8;                // 0..3
    int b = bh >> 4, h = bh & 15;
    size_t base = (size_t)b * S * D3;

    u16* pout = quar == 0 ? p0 : (quar == 1 ? p1 : (quar == 2 ? p2 : p3));

    int rK0 = t >> 3, gK = t & 7;
    int rK1 = rK0 + 32;
    size_t koff0 = (size_t)rK0 * D3 + (size_t)((gK ^ (rK0 & 7)) * 8);
    size_t koff1 = (size_t)rK1 * D3 + (size_t)((gK ^ (rK1 & 7)) * 8);
    const u16* kbase = qkv + base + Dm + h * 64;
    const u16* vbase = qkv + base + 2 * Dm + h * 64 + w * 16;

    constexpr float cexp = 0.18033688011112042f;   // 0.125 * log2(e)
    constexpr float THR = 64.0f;                    // defer-max threshold
    int xg = l32 & 7;

    #pragma unroll 1
    for (int ph = 0; ph < 2; ++ph) {
        int qt = ph ? (15 - pr) : pr;
        int qb = qt * 128 + w * 32;
        int nst = 2 * (qt + 1);
        int c0 = (nst * quar) >> 2;
        int c1 = (nst * (quar + 1)) >> 2;

        f32x16 O0 = {}, O1 = {};
        float m = -1e30f, lr = 0.f;

        if (c0 < c1) {
            s16x8 qf[4];
            const u16* qp = qkv + base + (size_t)(qb + l32) * D3 + h * 64 + hi * 8;
            #pragma unroll
            for (int kk = 0; kk < 4; ++kk)
                qf[kk] = *(const s16x8*)(qp + kk * 16);

            size_t kc0 = (size_t)c0 * 64 * D3;
            gld_lds16(kbase + kc0 + koff0, &Kl[0][w * 512]);
            gld_lds16(kbase + kc0 + koff1, &Kl[0][2048 + w * 512]);
            {
                const u16* vp = vbase + (size_t)(c0 * 64 + l) * D3;
                s16x8 pv0 = *(const s16x8*)vp;
                s16x8 pv1 = *(const s16x8*)(vp + 8);
                #pragma unroll
                for (int e = 0; e < 8; ++e) {
                    int d0 = w * 16 + e, d1 = w * 16 + 8 + e;
                    Vt[0][d0 * 64 + (l ^ ((d0 & 7) << 3))] = (u16)pv0[e];
                    Vt[0][d1 * 64 + (l ^ ((d1 & 7) << 3))] = (u16)pv1[e];
                }
            }
            __syncthreads();

            #pragma unroll 1
            for (int sc = c0; sc < c1; ++sc) {
                int cur = (sc - c0) & 1;
                bool pre = (sc + 1 < c1);
                s16x8 v0, v1;
                if (pre) {
                    size_t koffc = (size_t)(sc + 1) * 64 * D3;
                    gld_lds16(kbase + koffc + koff0, &Kl[cur ^ 1][w * 512]);
                    gld_lds16(kbase + koffc + koff1, &Kl[cur ^ 1][2048 + w * 512]);
                    const u16* vp = vbase + (size_t)((sc + 1) * 64 + l) * D3;
                    v0 = *(const s16x8*)vp;
                    v1 = *(const s16x8*)(vp + 8);
                }

                int kvb = sc * 64;
                int navail = ((qb - kvb) >> 5) + 1;
                if (navail > 0) {
                    if (navail > 2) navail = 2;
                    const u16* Kc = Kl[cur];
                    const u16* Vc = Vt[cur];
                    f32x16 sa0 = {}, sa1 = {};
                    #pragma unroll
                    for (int kk = 0; kk < 4; ++kk) {
                        s16x8 kf = *(const s16x8*)&Kc[l32 * 64 + (((2 * kk + hi) ^ xg) * 8)];
                        sa0 = mfma32(kf, qf[kk], sa0);
                    }
                    if (navail == 2) {
                        #pragma unroll
                        for (int kk = 0; kk < 4; ++kk) {
                            s16x8 kf = *(const s16x8*)&Kc[(32 + l32) * 64 + (((2 * kk + hi) ^ xg) * 8)];
                            sa1 = mfma32(kf, qf[kk], sa1);
                        }
                    }
                    bool diag0 = (kvb == qb);
                    bool diag1 = (kvb + 32 == qb);
                    float p[32];
                    float mx = -1e30f;
                    #pragma unroll
                    for (int reg = 0; reg < 16; ++reg) {
                        int kvloc = (reg & 3) + 8 * (reg >> 2) + 4 * hi;
                        float s0 = sa0[reg];
                        if (diag0 && kvloc > l32) s0 = -1e30f;
                        p[reg] = s0;
                        mx = fmaxf(mx, s0);
                    }
                    if (navail == 2) {
                        #pragma unroll
                        for (int reg = 0; reg < 16; ++reg) {
                            int kvloc = (reg & 3) + 8 * (reg >> 2) + 4 * hi;
                            float s1 = sa1[reg];
                            if (diag1 && kvloc > l32) s1 = -1e30f;
                            p[16 + reg] = s1;
                            mx = fmaxf(mx, s1);
                        }
                    }
                    mx = fmaxf(mx, __shfl_xor(mx, 32));
                    if (!__all(mx <= m + THR)) {          // defer-max (T13)
                        float mn = fmaxf(m, mx);
                        float a_ = exp2f(cexp * (m - mn));
                        m = mn;
                        #pragma unroll
                        for (int reg = 0; reg < 16; ++reg) {
                            int src = (reg & 3) + 8 * (reg >> 2) + 4 * hi;
                            float aq = __shfl(a_, src);
                            O0[reg] *= aq;
                            O1[reg] *= aq;
                        }
                        lr *= a_;
                    }
                    float cm = cexp * m;                  // exp2(cexp*p - cm)
                    float rs = 0.f;
                    #pragma unroll
                    for (int reg = 0; reg < 16; ++reg) {
                        p[reg] = exp2f(fmaf(cexp, p[reg], -cm));
                        rs += p[reg];
                    }
                    if (navail == 2) {
                        #pragma unroll
                        for (int reg = 16; reg < 32; ++reg) {
                            p[reg] = exp2f(fmaf(cexp, p[reg], -cm));
                            rs += p[reg];
                        }
                    }
                    rs += __shfl_xor(rs, 32);
                    lr += rs;

                    #pragma unroll
                    for (int c = 0; c < 4; ++c) {
                        if (c < navail * 2) {
                            int pb = (c >> 1) * 16 + (c & 1) * 8;
                            int pk01 = cvtpk(p[pb + 0], p[pb + 1]);
                            int pk23 = cvtpk(p[pb + 2], p[pb + 3]);
                            int pk45 = cvtpk(p[pb + 4], p[pb + 5]);
                            int pk67 = cvtpk(p[pb + 6], p[pb + 7]);
                            int sx01 = __shfl_xor(pk01, 32);
                            int sx23 = __shfl_xor(pk23, 32);
                            int sx45 = __shfl_xor(pk45, 32);
                            int sx67 = __shfl_xor(pk67, 32);
                            union { int i[4]; s16x8 v; } u;
                            u.i[0] = hi ? sx45 : pk01;
                            u.i[1] = hi ? sx67 : pk23;
                            u.i[2] = hi ? pk45 : sx01;
                            u.i[3] = hi ? pk67 : sx23;
                            int go = ((c * 2 + hi) ^ xg) * 8;
                            s16x8 vb0 = *(const s16x8*)&Vc[l32 * 64 + go];
                            O0 = mfma32(u.v, vb0, O0);
                            s16x8 vb1 = *(const s16x8*)&Vc[(32 + l32) * 64 + go];
                            O1 = mfma32(u.v, vb1, O1);
                        }
                    }
                }

                if (pre) {
                    #pragma unroll
                    for (int e = 0; e < 8; ++e) {
                        int d0 = w * 16 + e, d1 = w * 16 + 8 + e;
                        Vt[cur ^ 1][d0 * 64 + (l ^ ((d0 & 7) << 3))] = (u16)v0[e];
                        Vt[cur ^ 1][d1 * 64 + (l ^ ((d1 & 7) << 3))] = (u16)v1[e];
                    }
                }
                __syncthreads();
            }
        }

        size_t obase = (size_t)b * S * 1024 + h * 64;
        #pragma unroll
        for (int reg = 0; reg < 16; ++reg) {
            int src = (reg & 3) + 8 * (reg >> 2) + 4 * hi;
            size_t row = obase + (size_t)(qb + src) * 1024;
            pout[row + l32] = f2b(O0[reg]);
            pout[row + 32 + l32] = f2b(O1[reg]);
        }
        if (hi == 0) {
            float2 st; st.x = m; st.y = lr;
            stats[quar * 65536 + ((b * 2048 + qb + l32) * 16 + h)] = st;
        }
    }
}

// ------------------------- attention partial merge (x4) ---------------------
__global__ __launch_bounds__(256) void merge_attn(u16* __restrict__ p0,
                                                  const u16* __restrict__ p1,
                                                  const u16* __restrict__ p2,
                                                  const u16* __restrict__ p3,
                                                  const float2* __restrict__ stats) {
    constexpr float cexp = 0.18033688011112042f;
    int gid = blockIdx.x * 256 + threadIdx.x;    // [0, 65536*4)
    int rh = gid >> 2;
    int dc = (gid & 3) * 16;
    int R = rh >> 4, h = rh & 15;
    size_t addr = (size_t)R * 1024 + h * 64 + dc;

    float2 s0 = stats[rh];
    float2 s1 = stats[65536 + rh];
    float2 s2 = stats[131072 + rh];
    float2 s3 = stats[196608 + rh];
    float M = fmaxf(fmaxf(s0.x, s1.x), fmaxf(s2.x, s3.x));
    float a0 = exp2f(cexp * (s0.x - M));
    float a1 = exp2f(cexp * (s1.x - M));
    float a2 = exp2f(cexp * (s2.x - M));
    float a3 = exp2f(cexp * (s3.x - M));
    float inv = 1.f / (a0 * s0.y + a1 * s1.y + a2 * s2.y + a3 * s3.y);
    a0 *= inv; a1 *= inv; a2 *= inv; a3 *= inv;

    u16x4 o[4];
    #pragma unroll
    for (int j = 0; j < 4; ++j) {
        u16x4 q0 = *(const u16x4*)(p0 + addr + j * 4);
        u16x4 q1 = *(const u16x4*)(p1 + addr + j * 4);
        u16x4 q2 = *(const u16x4*)(p2 + addr + j * 4);
        u16x4 q3 = *(const u16x4*)(p3 + addr + j * 4);
        #pragma unroll
        for (int e = 0; e < 4; ++e)
            o[j][e] = f2b(a0 * b2f(q0[e]) + a1 * b2f(q1[e]) +
                          a2 * b2f(q2[e]) + a3 * b2f(q3[e]));
    }
    #pragma unroll
    for (int j = 0; j < 4; ++j)
        *(u16x4*)(p0 + addr + j * 4) = o[j];
}

// --------------------- residual + LayerNorm (row = 1024) --------------------
template<bool WB>
__global__ __launch_bounds__(256) void resln(const float* __restrict__ xa,
                                             const float* __restrict__ xb2,
                                             const float* __restrict__ g,
                                             const float* __restrict__ be,
                                             float* __restrict__ outf,
                                             u16* __restrict__ outb) {
    int row = blockIdx.x;
    int t = threadIdx.x;
    size_t base = (size_t)row * 1024 + t * 4;
    float4 va = *(const float4*)(xa + base);
    float4 vb = *(const float4*)(xb2 + base);
    float v0 = va.x + vb.x, v1 = va.y + vb.y, v2 = va.z + vb.z, v3 = va.w + vb.w;
    float s1 = v0 + v1 + v2 + v3;
    float s2 = v0 * v0 + v1 * v1 + v2 * v2 + v3 * v3;
    #pragma unroll
    for (int off = 32; off >= 1; off >>= 1) {
        s1 += __shfl_down(s1, off);
        s2 += __shfl_down(s2, off);
    }
    __shared__ float r1[4], r2[4];
    if ((t & 63) == 0) { r1[t >> 6] = s1; r2[t >> 6] = s2; }
    __syncthreads();
    s1 = r1[0] + r1[1] + r1[2] + r1[3];
    s2 = r2[0] + r2[1] + r2[2] + r2[3];
    float mean = s1 * (1.f / 1024.f);
    float var = fmaxf((s2 - 1024.f * mean * mean) * (1.f / 1023.f), 0.f);
    float inv = 1.f / (sqrtf(var) + 1e-6f);
    int col = t * 4;
    float y0 = g[col + 0] * ((v0 - mean) * inv) + be[col + 0];
    float y1 = g[col + 1] * ((v1 - mean) * inv) + be[col + 1];
    float y2 = g[col + 2] * ((v2 - mean) * inv) + be[col + 2];
    float y3 = g[col + 3] * ((v3 - mean) * inv) + be[col + 3];
    float4 o = {y0, y1, y2, y3};
    *(float4*)(outf + base) = o;
    if constexpr (WB) {
        u16x4 ob = {f2b(y0), f2b(y1), f2b(y2), f2b(y3)};
        *(u16x4*)(outb + base) = ob;
    }
}

// ---------------------------------------------------------------------------
extern "C" void kernel_launch(void* const* d_in, const int* in_sizes, int n_in,
                              void* d_out, int out_size, void* d_ws, size_t ws_size,
                              hipStream_t stream) {
    (void)in_sizes; (void)n_in; (void)out_size; (void)ws_size;
    const float* x       = (const float*)d_in[0];
    const float* w_attn  = (const float*)d_in[1];
    const float* b_attn  = (const float*)d_in[2];
    const float* w_aproj = (const float*)d_in[3];
    const float* b_aproj = (const float*)d_in[4];
    const float* g1      = (const float*)d_in[5];
    const float* b1      = (const float*)d_in[6];
    const float* w_fc    = (const float*)d_in[7];
    const float* b_fc    = (const float*)d_in[8];
    const float* w_mproj = (const float*)d_in[9];
    const float* b_mproj = (const float*)d_in[10];
    const float* g2      = (const float*)d_in[11];
    const float* b2      = (const float*)d_in[12];
    float* out = (float*)d_out;

    constexpr int M = 4096;           // B*S
    constexpr int D = 1024;

    char* ws = (char*)d_ws;
    u16*   slotA = (u16*)ws;                         // 32 MiB: qkv -> h
    char*  pB    = ws + (32u << 20);                 //  8 MiB: xb -> part0/abuf -> nb
    char*  pC    = ws + (40u << 20);                 //  8 MiB: part1 -> wT
    char*  pD    = ws + (48u << 20);                 // 16 MiB: part2+part3 -> aout -> mout
    char*  pE    = ws + (64u << 20);                 // 16 MiB: stats -> nbuf (fp32)

    u16*   xb    = (u16*)pB;
    u16*   wT    = (u16*)pC;
    u16*   qkv   = slotA;
    u16*   part0 = (u16*)pB;                         // becomes merged abuf
    u16*   part1 = (u16*)pC;
    u16*   part2 = (u16*)pD;
    u16*   part3 = (u16*)(pD + (8u << 20));
    float2* stat = (float2*)pE;
    u16*   abuf  = (u16*)pB;
    float* aout  = (float*)pD;
    float* nbuf  = (float*)pE;
    u16*   nb    = (u16*)pB;
    u16*   h     = slotA;
    float* mout  = (float*)pD;

    dim3 blk(256);

    cvt_bf16<<<dim3(4096), blk, 0, stream>>>(x, xb, M * D / 4);

    transpose_bf16<<<dim3(3072 / 32, 1024 / 32), blk, 0, stream>>>(w_attn, wT, 1024, 3072);
    gemm_pl<128, false, u16><<<dim3((M / 128) * (3072 / 128)), blk, 0, stream>>>(
        xb, wT, b_attn, qkv, M, 3072, 1024, 3072);

    attn_kernel<<<dim3(1024), blk, 0, stream>>>(qkv, part0, part1, part2, part3, stat);
    merge_attn<<<dim3(1024), blk, 0, stream>>>(part0, part1, part2, part3, stat);

    transpose_bf16<<<dim3(1024 / 32, 1024 / 32), blk, 0, stream>>>(w_aproj, wT, 1024, 1024);
    gemm_pl<64, false, float><<<dim3((M / 128) * (1024 / 64)), blk, 0, stream>>>(
        abuf, wT, b_aproj, aout, M, 1024, 1024, 1024);

    resln<true><<<dim3(M), blk, 0, stream>>>(x, aout, g1, b1, nbuf, nb);

    transpose_bf16<<<dim3(4096 / 32, 1024 / 32), blk, 0, stream>>>(w_fc, wT, 1024, 4096);
    gemm_pl<128, true, u16><<<dim3((M / 128) * (4096 / 128)), blk, 0, stream>>>(
        nb, wT, b_fc, h, M, 4096, 1024, 4096);

    transpose_bf16<<<dim3(1024 / 32, 4096 / 32), blk, 0, stream>>>(w_mproj, wT, 4096, 1024);
    gemm_pl<64, false, float><<<dim3((M / 128) * (1024 / 64)), blk, 0, stream>>>(
        h, wT, b_mproj, mout, M, 1024, 4096, 1024);

    resln<false><<<dim3(M), blk, 0, stream>>>(nbuf, mout, g2, b2, out, nullptr);
}